// Round 1
// baseline (1662.208 us; speedup 1.0000x reference)
//
#include <hip/hip_runtime.h>

#define IN_DIM 128
#define HID    128
#define NCLS   4

// ---------------- Layer 0: H = relu(X @ W0^T + b0) ----------------
// Block: 256 threads, computes 128 rows x 128 cols. Per-thread 8x8 tile.
// Thread (tx=tid&15, ty=tid>>4) owns rows {ty+16j} cols {8tx..8tx+7}.
__global__ __launch_bounds__(256) void gnn_lin0(const float* __restrict__ X,
                                                const float* __restrict__ W,
                                                const float* __restrict__ Bv,
                                                float* __restrict__ H, int M)
{
    __shared__ float As[128 * 132];   // [r][k], row stride 132
    __shared__ float Ws[128 * 132];   // W^T: Ws[k*132+n] = W[n*128+k]

    const int tid = threadIdx.x;
    const int bm  = blockIdx.x << 7;

    #pragma unroll 4
    for (int it = 0; it < 64; ++it) {            // 128*128 / 256
        int i = tid + (it << 8);
        int n = i >> 7, k = i & 127;
        Ws[k * 132 + n] = W[i];
    }
    #pragma unroll 4
    for (int it = 0; it < 16; ++it) {            // 128 rows * 32 float4
        int i4 = tid + (it << 8);
        int r = i4 >> 5, c4 = i4 & 31;
        int row = bm + r;
        float4 v = make_float4(0.f, 0.f, 0.f, 0.f);
        if (row < M) v = ((const float4*)X)[row * 32 + c4];
        *(float4*)&As[r * 132 + (c4 << 2)] = v;
    }
    __syncthreads();

    const int tx = tid & 15, ty = tid >> 4;
    float acc[8][8];
    #pragma unroll
    for (int j = 0; j < 8; ++j)
        #pragma unroll
        for (int n = 0; n < 8; ++n) acc[j][n] = 0.f;

    for (int k = 0; k < 128; k += 4) {
        float a4[8][4];
        #pragma unroll
        for (int j = 0; j < 8; ++j) {
            float4 t = *(const float4*)&As[(ty + (j << 4)) * 132 + k];
            a4[j][0] = t.x; a4[j][1] = t.y; a4[j][2] = t.z; a4[j][3] = t.w;
        }
        #pragma unroll
        for (int kk = 0; kk < 4; ++kk) {
            float4 t0 = *(const float4*)&Ws[(k + kk) * 132 + (tx << 3)];
            float4 t1 = *(const float4*)&Ws[(k + kk) * 132 + (tx << 3) + 4];
            float w[8] = {t0.x, t0.y, t0.z, t0.w, t1.x, t1.y, t1.z, t1.w};
            #pragma unroll
            for (int j = 0; j < 8; ++j)
                #pragma unroll
                for (int n = 0; n < 8; ++n)
                    acc[j][n] = fmaf(a4[j][kk], w[n], acc[j][n]);
        }
    }

    float4 b0 = ((const float4*)Bv)[tx * 2];
    float4 b1 = ((const float4*)Bv)[tx * 2 + 1];
    float bvv[8] = {b0.x, b0.y, b0.z, b0.w, b1.x, b1.y, b1.z, b1.w};
    #pragma unroll
    for (int j = 0; j < 8; ++j) {
        int row = bm + ty + (j << 4);
        if (row < M) {
            float o[8];
            #pragma unroll
            for (int n = 0; n < 8; ++n) o[n] = fmaxf(acc[j][n] + bvv[n], 0.f);
            float* dst = H + (size_t)row * HID + (tx << 3);
            *(float4*)dst       = make_float4(o[0], o[1], o[2], o[3]);
            *(float4*)(dst + 4) = make_float4(o[4], o[5], o[6], o[7]);
        }
    }
}

// ---------------- Edge scatter: agg[row] += h[col], deg[row] += 1 ----------------
__global__ __launch_bounds__(256) void gnn_scatter(const int* __restrict__ rows,
                                                   const int* __restrict__ cols,
                                                   const float* __restrict__ H,
                                                   float* __restrict__ agg,
                                                   float* __restrict__ deg, int E)
{
    int g = (blockIdx.x * 256 + threadIdx.x) >> 5;   // edge id (32 lanes/edge)
    int l = threadIdx.x & 31;
    if (g >= E) return;
    int r = rows[g];
    int c = cols[g];
    float4 v = ((const float4*)H)[(size_t)c * 32 + l];
    float* dst = agg + (size_t)r * HID + (l << 2);
    atomicAdd(dst + 0, v.x);
    atomicAdd(dst + 1, v.y);
    atomicAdd(dst + 2, v.z);
    atomicAdd(dst + 3, v.w);
    if (l == 0) atomicAdd(deg + r, 1.0f);
}

// ---------------- Layer 1 + classifier ----------------
// in = h + agg/max(deg,1);  h2 = relu(in @ W1^T + b1);  out = h2 @ Wc^T + bc
__global__ __launch_bounds__(256) void gnn_lin1_cls(const float* __restrict__ Hin,
                                                    const float* __restrict__ Agg,
                                                    const float* __restrict__ Deg,
                                                    const float* __restrict__ W,
                                                    const float* __restrict__ Bv,
                                                    const float* __restrict__ Wc,
                                                    const float* __restrict__ bc,
                                                    float* __restrict__ Out, int M)
{
    __shared__ float As[128 * 132];
    __shared__ float Ws[128 * 132];

    const int tid = threadIdx.x;
    const int bm  = blockIdx.x << 7;

    #pragma unroll 4
    for (int it = 0; it < 64; ++it) {
        int i = tid + (it << 8);
        int n = i >> 7, k = i & 127;
        Ws[k * 132 + n] = W[i];
    }
    #pragma unroll 4
    for (int it = 0; it < 16; ++it) {
        int i4 = tid + (it << 8);
        int r = i4 >> 5, c4 = i4 & 31;
        int row = bm + r;
        float4 v = make_float4(0.f, 0.f, 0.f, 0.f);
        if (row < M) {
            float4 hv = ((const float4*)Hin)[(size_t)row * 32 + c4];
            float4 av = ((const float4*)Agg)[(size_t)row * 32 + c4];
            float rd = 1.0f / fmaxf(Deg[row], 1.0f);
            v.x = hv.x + av.x * rd;
            v.y = hv.y + av.y * rd;
            v.z = hv.z + av.z * rd;
            v.w = hv.w + av.w * rd;
        }
        *(float4*)&As[r * 132 + (c4 << 2)] = v;
    }
    __syncthreads();

    const int tx = tid & 15, ty = tid >> 4;
    float acc[8][8];
    #pragma unroll
    for (int j = 0; j < 8; ++j)
        #pragma unroll
        for (int n = 0; n < 8; ++n) acc[j][n] = 0.f;

    for (int k = 0; k < 128; k += 4) {
        float a4[8][4];
        #pragma unroll
        for (int j = 0; j < 8; ++j) {
            float4 t = *(const float4*)&As[(ty + (j << 4)) * 132 + k];
            a4[j][0] = t.x; a4[j][1] = t.y; a4[j][2] = t.z; a4[j][3] = t.w;
        }
        #pragma unroll
        for (int kk = 0; kk < 4; ++kk) {
            float4 t0 = *(const float4*)&Ws[(k + kk) * 132 + (tx << 3)];
            float4 t1 = *(const float4*)&Ws[(k + kk) * 132 + (tx << 3) + 4];
            float w[8] = {t0.x, t0.y, t0.z, t0.w, t1.x, t1.y, t1.z, t1.w};
            #pragma unroll
            for (int j = 0; j < 8; ++j)
                #pragma unroll
                for (int n = 0; n < 8; ++n)
                    acc[j][n] = fmaf(a4[j][kk], w[n], acc[j][n]);
        }
    }

    // h2 = relu(acc + b1), kept in registers
    float4 b0 = ((const float4*)Bv)[tx * 2];
    float4 b1v = ((const float4*)Bv)[tx * 2 + 1];
    float bvv[8] = {b0.x, b0.y, b0.z, b0.w, b1v.x, b1v.y, b1v.z, b1v.w};
    #pragma unroll
    for (int j = 0; j < 8; ++j)
        #pragma unroll
        for (int n = 0; n < 8; ++n)
            acc[j][n] = fmaxf(acc[j][n] + bvv[n], 0.f);

    // classifier partials over this thread's 8-col slice
    float p[8][4];
    #pragma unroll
    for (int c = 0; c < 4; ++c) {
        float4 c0 = *(const float4*)&Wc[c * HID + (tx << 3)];
        float4 c1 = *(const float4*)&Wc[c * HID + (tx << 3) + 4];
        float wcv[8] = {c0.x, c0.y, c0.z, c0.w, c1.x, c1.y, c1.z, c1.w};
        #pragma unroll
        for (int j = 0; j < 8; ++j) {
            float s = 0.f;
            #pragma unroll
            for (int n = 0; n < 8; ++n) s = fmaf(acc[j][n], wcv[n], s);
            p[j][c] = s;
        }
    }
    // reduce across the 16 tx lanes (same ty => consecutive lanes)
    #pragma unroll
    for (int off = 1; off < 16; off <<= 1) {
        #pragma unroll
        for (int j = 0; j < 8; ++j)
            #pragma unroll
            for (int c = 0; c < 4; ++c)
                p[j][c] += __shfl_xor(p[j][c], off);
    }
    if (tx == 0) {
        float4 bcv = *(const float4*)bc;
        #pragma unroll
        for (int j = 0; j < 8; ++j) {
            int row = bm + ty + (j << 4);
            if (row < M) {
                ((float4*)Out)[row] = make_float4(p[j][0] + bcv.x, p[j][1] + bcv.y,
                                                  p[j][2] + bcv.z, p[j][3] + bcv.w);
            }
        }
    }
}

extern "C" void kernel_launch(void* const* d_in, const int* in_sizes, int n_in,
                              void* d_out, int out_size, void* d_ws, size_t ws_size,
                              hipStream_t stream)
{
    const float* x  = (const float*)d_in[0];
    const int*   ei = (const int*)  d_in[1];
    const float* W0 = (const float*)d_in[2];
    const float* b0 = (const float*)d_in[3];
    const float* W1 = (const float*)d_in[4];
    const float* b1 = (const float*)d_in[5];
    const float* Wc = (const float*)d_in[6];
    const float* bc = (const float*)d_in[7];
    float* out = (float*)d_out;

    const int M = in_sizes[0] / IN_DIM;   // 100000
    const int E = in_sizes[1] / 2;        // 800000

    float* h   = (float*)d_ws;                       // M*128
    float* agg = h   + (size_t)M * HID;              // M*128
    float* deg = agg + (size_t)M * HID;              // M

    // zero agg + deg (contiguous)
    hipMemsetAsync(agg, 0, ((size_t)M * HID + M) * sizeof(float), stream);

    const int gridM = (M + 127) / 128;
    gnn_lin0<<<gridM, 256, 0, stream>>>(x, W0, b0, h, M);
    gnn_scatter<<<(E + 7) / 8, 256, 0, stream>>>(ei, ei + E, h, agg, deg, E);
    gnn_lin1_cls<<<gridM, 256, 0, stream>>>(h, agg, deg, W1, b1, Wc, bc, out, M);
}

// Round 2
// 425.335 us; speedup vs baseline: 3.9080x; 3.9080x over previous
//
#include <hip/hip_runtime.h>

#define IN_DIM 128
#define HID    128
#define NCLS   4

// ---------------- Layer 0: H = relu(X @ W0^T + b0) ----------------
__global__ __launch_bounds__(256) void gnn_lin0(const float* __restrict__ X,
                                                const float* __restrict__ W,
                                                const float* __restrict__ Bv,
                                                float* __restrict__ H, int M)
{
    __shared__ float As[128 * 132];   // [r][k], row stride 132
    __shared__ float Ws[128 * 132];   // W^T: Ws[k*132+n] = W[n*128+k]

    const int tid = threadIdx.x;
    const int bm  = blockIdx.x << 7;

    #pragma unroll 4
    for (int it = 0; it < 64; ++it) {            // 128*128 / 256
        int i = tid + (it << 8);
        int n = i >> 7, k = i & 127;
        Ws[k * 132 + n] = W[i];
    }
    #pragma unroll 4
    for (int it = 0; it < 16; ++it) {            // 128 rows * 32 float4
        int i4 = tid + (it << 8);
        int r = i4 >> 5, c4 = i4 & 31;
        int row = bm + r;
        float4 v = make_float4(0.f, 0.f, 0.f, 0.f);
        if (row < M) v = ((const float4*)X)[(size_t)row * 32 + c4];
        *(float4*)&As[r * 132 + (c4 << 2)] = v;
    }
    __syncthreads();

    const int tx = tid & 15, ty = tid >> 4;
    float acc[8][8];
    #pragma unroll
    for (int j = 0; j < 8; ++j)
        #pragma unroll
        for (int n = 0; n < 8; ++n) acc[j][n] = 0.f;

    for (int k = 0; k < 128; k += 4) {
        float a4[8][4];
        #pragma unroll
        for (int j = 0; j < 8; ++j) {
            float4 t = *(const float4*)&As[(ty + (j << 4)) * 132 + k];
            a4[j][0] = t.x; a4[j][1] = t.y; a4[j][2] = t.z; a4[j][3] = t.w;
        }
        #pragma unroll
        for (int kk = 0; kk < 4; ++kk) {
            float4 t0 = *(const float4*)&Ws[(k + kk) * 132 + (tx << 3)];
            float4 t1 = *(const float4*)&Ws[(k + kk) * 132 + (tx << 3) + 4];
            float w[8] = {t0.x, t0.y, t0.z, t0.w, t1.x, t1.y, t1.z, t1.w};
            #pragma unroll
            for (int j = 0; j < 8; ++j)
                #pragma unroll
                for (int n = 0; n < 8; ++n)
                    acc[j][n] = fmaf(a4[j][kk], w[n], acc[j][n]);
        }
    }

    float4 b0 = ((const float4*)Bv)[tx * 2];
    float4 b1 = ((const float4*)Bv)[tx * 2 + 1];
    float bvv[8] = {b0.x, b0.y, b0.z, b0.w, b1.x, b1.y, b1.z, b1.w};
    #pragma unroll
    for (int j = 0; j < 8; ++j) {
        int row = bm + ty + (j << 4);
        if (row < M) {
            float o[8];
            #pragma unroll
            for (int n = 0; n < 8; ++n) o[n] = fmaxf(acc[j][n] + bvv[n], 0.f);
            float* dst = H + (size_t)row * HID + (tx << 3);
            *(float4*)dst       = make_float4(o[0], o[1], o[2], o[3]);
            *(float4*)(dst + 4) = make_float4(o[4], o[5], o[6], o[7]);
        }
    }
}

// ---------------- CSR build ----------------
__global__ __launch_bounds__(256) void count_deg(const int* __restrict__ rows,
                                                 int* __restrict__ deg, int E)
{
    int e = blockIdx.x * 256 + threadIdx.x;
    if (e < E) atomicAdd(&deg[rows[e]], 1);
}

__global__ __launch_bounds__(256) void scan_blocks(const int* __restrict__ deg,
                                                   int* __restrict__ off,
                                                   int* __restrict__ bsum, int M)
{
    __shared__ int sh[256];
    int i = blockIdx.x * 256 + threadIdx.x;
    int v = (i < M) ? deg[i] : 0;
    sh[threadIdx.x] = v;
    __syncthreads();
    #pragma unroll
    for (int d = 1; d < 256; d <<= 1) {
        int t = (threadIdx.x >= d) ? sh[threadIdx.x - d] : 0;
        __syncthreads();
        sh[threadIdx.x] += t;
        __syncthreads();
    }
    if (i < M) off[i] = sh[threadIdx.x] - v;          // exclusive within block
    if (threadIdx.x == 255) bsum[blockIdx.x] = sh[255];
}

__global__ __launch_bounds__(512) void scan_bsum(int* __restrict__ bsum, int NB)
{
    __shared__ int sh[512];
    int v = (threadIdx.x < NB) ? bsum[threadIdx.x] : 0;
    sh[threadIdx.x] = v;
    __syncthreads();
    #pragma unroll
    for (int d = 1; d < 512; d <<= 1) {
        int t = (threadIdx.x >= d) ? sh[threadIdx.x - d] : 0;
        __syncthreads();
        sh[threadIdx.x] += t;
        __syncthreads();
    }
    if (threadIdx.x < NB) bsum[threadIdx.x] = sh[threadIdx.x] - v;  // exclusive
}

__global__ __launch_bounds__(256) void add_off(int* __restrict__ off,
                                               const int* __restrict__ bsum,
                                               int* __restrict__ pos, int M)
{
    int i = blockIdx.x * 256 + threadIdx.x;
    if (i < M) {
        int o = off[i] + bsum[i >> 8];
        off[i] = o;
        pos[i] = o;
    }
}

__global__ __launch_bounds__(256) void fill_csr(const int* __restrict__ rows,
                                                const int* __restrict__ cols,
                                                int* __restrict__ pos,
                                                int* __restrict__ col_sorted, int E)
{
    int e = blockIdx.x * 256 + threadIdx.x;
    if (e < E) {
        int p = atomicAdd(&pos[rows[e]], 1);
        col_sorted[p] = cols[e];
    }
}

// ---------------- Aggregation: agg[i] = h[i] + (sum_{e in N(i)} h[col_e]) / max(deg,1)
// One 32-lane group per node; lane holds one float4 (128 ch = 32 float4).
__global__ __launch_bounds__(256) void gnn_aggregate(const float* __restrict__ H,
                                                     const int* __restrict__ off,
                                                     const int* __restrict__ deg,
                                                     const int* __restrict__ col_sorted,
                                                     float* __restrict__ Agg, int M)
{
    int gid  = blockIdx.x * 8 + (threadIdx.x >> 5);
    int lane = threadIdx.x & 31;
    if (gid >= M) return;

    const float4* H4 = (const float4*)H;
    int start = off[gid];
    int d     = deg[gid];

    float4 acc = make_float4(0.f, 0.f, 0.f, 0.f);
    for (int e = start; e < start + d; ++e) {
        int c = col_sorted[e];
        float4 v = H4[(size_t)c * 32 + lane];
        acc.x += v.x; acc.y += v.y; acc.z += v.z; acc.w += v.w;
    }
    float inv = 1.0f / fmaxf((float)d, 1.0f);
    float4 hv = H4[(size_t)gid * 32 + lane];
    float4 o = make_float4(hv.x + acc.x * inv, hv.y + acc.y * inv,
                           hv.z + acc.z * inv, hv.w + acc.w * inv);
    ((float4*)Agg)[(size_t)gid * 32 + lane] = o;
}

// ---------------- Layer 1 + classifier ----------------
// in = Agg (residual+norm already fused); h2 = relu(in @ W1^T + b1); out = h2 @ Wc^T + bc
__global__ __launch_bounds__(256) void gnn_lin1_cls(const float* __restrict__ Ain,
                                                    const float* __restrict__ W,
                                                    const float* __restrict__ Bv,
                                                    const float* __restrict__ Wc,
                                                    const float* __restrict__ bc,
                                                    float* __restrict__ Out, int M)
{
    __shared__ float As[128 * 132];
    __shared__ float Ws[128 * 132];

    const int tid = threadIdx.x;
    const int bm  = blockIdx.x << 7;

    #pragma unroll 4
    for (int it = 0; it < 64; ++it) {
        int i = tid + (it << 8);
        int n = i >> 7, k = i & 127;
        Ws[k * 132 + n] = W[i];
    }
    #pragma unroll 4
    for (int it = 0; it < 16; ++it) {
        int i4 = tid + (it << 8);
        int r = i4 >> 5, c4 = i4 & 31;
        int row = bm + r;
        float4 v = make_float4(0.f, 0.f, 0.f, 0.f);
        if (row < M) v = ((const float4*)Ain)[(size_t)row * 32 + c4];
        *(float4*)&As[r * 132 + (c4 << 2)] = v;
    }
    __syncthreads();

    const int tx = tid & 15, ty = tid >> 4;
    float acc[8][8];
    #pragma unroll
    for (int j = 0; j < 8; ++j)
        #pragma unroll
        for (int n = 0; n < 8; ++n) acc[j][n] = 0.f;

    for (int k = 0; k < 128; k += 4) {
        float a4[8][4];
        #pragma unroll
        for (int j = 0; j < 8; ++j) {
            float4 t = *(const float4*)&As[(ty + (j << 4)) * 132 + k];
            a4[j][0] = t.x; a4[j][1] = t.y; a4[j][2] = t.z; a4[j][3] = t.w;
        }
        #pragma unroll
        for (int kk = 0; kk < 4; ++kk) {
            float4 t0 = *(const float4*)&Ws[(k + kk) * 132 + (tx << 3)];
            float4 t1 = *(const float4*)&Ws[(k + kk) * 132 + (tx << 3) + 4];
            float w[8] = {t0.x, t0.y, t0.z, t0.w, t1.x, t1.y, t1.z, t1.w};
            #pragma unroll
            for (int j = 0; j < 8; ++j)
                #pragma unroll
                for (int n = 0; n < 8; ++n)
                    acc[j][n] = fmaf(a4[j][kk], w[n], acc[j][n]);
        }
    }

    // h2 = relu(acc + b1), kept in registers
    float4 b0 = ((const float4*)Bv)[tx * 2];
    float4 b1v = ((const float4*)Bv)[tx * 2 + 1];
    float bvv[8] = {b0.x, b0.y, b0.z, b0.w, b1v.x, b1v.y, b1v.z, b1v.w};
    #pragma unroll
    for (int j = 0; j < 8; ++j)
        #pragma unroll
        for (int n = 0; n < 8; ++n)
            acc[j][n] = fmaxf(acc[j][n] + bvv[n], 0.f);

    // classifier partials over this thread's 8-col slice
    float p[8][4];
    #pragma unroll
    for (int c = 0; c < 4; ++c) {
        float4 c0 = *(const float4*)&Wc[c * HID + (tx << 3)];
        float4 c1 = *(const float4*)&Wc[c * HID + (tx << 3) + 4];
        float wcv[8] = {c0.x, c0.y, c0.z, c0.w, c1.x, c1.y, c1.z, c1.w};
        #pragma unroll
        for (int j = 0; j < 8; ++j) {
            float s = 0.f;
            #pragma unroll
            for (int n = 0; n < 8; ++n) s = fmaf(acc[j][n], wcv[n], s);
            p[j][c] = s;
        }
    }
    #pragma unroll
    for (int off = 1; off < 16; off <<= 1) {
        #pragma unroll
        for (int j = 0; j < 8; ++j)
            #pragma unroll
            for (int c = 0; c < 4; ++c)
                p[j][c] += __shfl_xor(p[j][c], off);
    }
    if (tx == 0) {
        float4 bcv = *(const float4*)bc;
        #pragma unroll
        for (int j = 0; j < 8; ++j) {
            int row = bm + ty + (j << 4);
            if (row < M) {
                ((float4*)Out)[row] = make_float4(p[j][0] + bcv.x, p[j][1] + bcv.y,
                                                  p[j][2] + bcv.z, p[j][3] + bcv.w);
            }
        }
    }
}

extern "C" void kernel_launch(void* const* d_in, const int* in_sizes, int n_in,
                              void* d_out, int out_size, void* d_ws, size_t ws_size,
                              hipStream_t stream)
{
    const float* x  = (const float*)d_in[0];
    const int*   ei = (const int*)  d_in[1];
    const float* W0 = (const float*)d_in[2];
    const float* b0 = (const float*)d_in[3];
    const float* W1 = (const float*)d_in[4];
    const float* b1 = (const float*)d_in[5];
    const float* Wc = (const float*)d_in[6];
    const float* bc = (const float*)d_in[7];
    float* out = (float*)d_out;

    const int M = in_sizes[0] / IN_DIM;   // 100000
    const int E = in_sizes[1] / 2;        // 800000
    const int NB = (M + 255) / 256;       // 391 scan blocks

    // workspace layout
    float* h   = (float*)d_ws;                          // M*128 floats
    float* agg = h + (size_t)M * HID;                   // M*128 floats
    int* deg_i = (int*)(agg + (size_t)M * HID);         // M ints
    int* off   = deg_i + M;                             // M ints
    int* pos   = off + M;                               // M ints
    int* bsum  = pos + M;                               // NB ints
    int* col_sorted = bsum + ((NB + 63) & ~63);         // E ints

    const int* rows = ei;
    const int* cols = ei + E;

    // zero degree counters only
    hipMemsetAsync(deg_i, 0, (size_t)M * sizeof(int), stream);

    const int gridM = (M + 127) / 128;
    const int gridE = (E + 255) / 256;
    const int gridN = (M + 255) / 256;

    gnn_lin0<<<gridM, 256, 0, stream>>>(x, W0, b0, h, M);
    count_deg<<<gridE, 256, 0, stream>>>(rows, deg_i, E);
    scan_blocks<<<gridN, 256, 0, stream>>>(deg_i, off, bsum, M);
    scan_bsum<<<1, 512, 0, stream>>>(bsum, NB);
    add_off<<<gridN, 256, 0, stream>>>(off, bsum, pos, M);
    fill_csr<<<gridE, 256, 0, stream>>>(rows, cols, pos, col_sorted, E);
    gnn_aggregate<<<(M + 7) / 8, 256, 0, stream>>>(h, off, deg_i, col_sorted, agg, M);
    gnn_lin1_cls<<<gridM, 256, 0, stream>>>(agg, W1, b1, Wc, bc, out, M);
}

// Round 3
// 355.670 us; speedup vs baseline: 4.6735x; 1.1959x over previous
//
#include <hip/hip_runtime.h>

#define IN_DIM 128
#define HID    128
#define NCLS   4

typedef __attribute__((ext_vector_type(8))) short bf16x8;
typedef __attribute__((ext_vector_type(4))) float f32x4;

// ---- fp32 -> bf16 hi/lo split helpers (RNE) ----
__device__ inline ushort f2bf(float x) {
    uint u = __builtin_bit_cast(uint, x);
    u += 0x7FFFu + ((u >> 16) & 1u);
    return (ushort)(u >> 16);
}
__device__ inline float bf2f(ushort h) {
    uint u = ((uint)h) << 16;
    return __builtin_bit_cast(float, u);
}

// ---------------- cast X: fp32 -> (hi, lo) bf16, zero-padded to Mpad rows ----------------
__global__ __launch_bounds__(256) void cast_x(const float* __restrict__ X,
                                              ushort* __restrict__ hi,
                                              ushort* __restrict__ lo,
                                              int n, int npad)
{
    int i = blockIdx.x * 256 + threadIdx.x;     // float4 index
    if (i * 4 >= npad) return;
    float4 v = make_float4(0.f, 0.f, 0.f, 0.f);
    if (i * 4 < n) v = ((const float4*)X)[i];
    ushort4 h4, l4;
    h4.x = f2bf(v.x); l4.x = f2bf(v.x - bf2f(h4.x));
    h4.y = f2bf(v.y); l4.y = f2bf(v.y - bf2f(h4.y));
    h4.z = f2bf(v.z); l4.z = f2bf(v.z - bf2f(h4.z));
    h4.w = f2bf(v.w); l4.w = f2bf(v.w - bf2f(h4.w));
    ((ushort4*)hi)[i] = h4;
    ((ushort4*)lo)[i] = l4;
}

// ---------------- cast W0 and W1 (each 128x128) ----------------
__global__ __launch_bounds__(256) void cast_w(const float* __restrict__ W0,
                                              const float* __restrict__ W1,
                                              ushort* __restrict__ w0h, ushort* __restrict__ w0l,
                                              ushort* __restrict__ w1h, ushort* __restrict__ w1l)
{
    int i = blockIdx.x * 256 + threadIdx.x;     // 0..32767
    float v = (i < 16384) ? W0[i] : W1[i - 16384];
    ushort h = f2bf(v);
    ushort l = f2bf(v - bf2f(h));
    if (i < 16384) { w0h[i] = h; w0l[i] = l; }
    else           { w1h[i - 16384] = h; w1l[i - 16384] = l; }
}

// ---------------- MFMA main loop: 64 rows x 128 cols per block, 4 waves (2x2) ----------------
// Wave computes 32 rows x 64 cols as 2x4 tiles of 16x16, K=128 in 4 k-tiles of 32.
// A-frag: lane holds A[rowbase+rt*16+(lane&15)][kt*32+(lane>>4)*8 + 0..7]  (16B global load)
// B-frag: lane holds W[colbase+nt*16+(lane&15)][kt*32+(lane>>4)*8 + 0..7]  (W itself is B^T)
// acc[rt][nt]: D[row=(lane>>4)*4+reg][col=lane&15]
__device__ inline void mfma_main(const ushort* __restrict__ Ahi, const ushort* __restrict__ Alo,
                                 const ushort* __restrict__ Whi, const ushort* __restrict__ Wlo,
                                 int rowbase, int colbase, int lr, int lk,
                                 f32x4 acc[2][4])
{
    #pragma unroll
    for (int kt = 0; kt < 4; ++kt) {
        const int ko = kt * 32 + lk * 8;
        bf16x8 ah[2], al[2];
        #pragma unroll
        for (int rt = 0; rt < 2; ++rt) {
            size_t ao = (size_t)(rowbase + rt * 16 + lr) * 128 + ko;
            ah[rt] = *(const bf16x8*)(Ahi + ao);
            al[rt] = *(const bf16x8*)(Alo + ao);
        }
        #pragma unroll
        for (int nt = 0; nt < 4; ++nt) {
            size_t bo = (size_t)(colbase + nt * 16 + lr) * 128 + ko;
            bf16x8 bh = *(const bf16x8*)(Whi + bo);
            bf16x8 bl = *(const bf16x8*)(Wlo + bo);
            #pragma unroll
            for (int rt = 0; rt < 2; ++rt) {
                acc[rt][nt] = __builtin_amdgcn_mfma_f32_16x16x32_bf16(ah[rt], bh, acc[rt][nt], 0, 0, 0);
                acc[rt][nt] = __builtin_amdgcn_mfma_f32_16x16x32_bf16(ah[rt], bl, acc[rt][nt], 0, 0, 0);
                acc[rt][nt] = __builtin_amdgcn_mfma_f32_16x16x32_bf16(al[rt], bh, acc[rt][nt], 0, 0, 0);
            }
        }
    }
}

// ---------------- Layer 0: H = relu(X @ W0^T + b0), fp32 out ----------------
__global__ __launch_bounds__(256) void gnn_lin0_mfma(const ushort* __restrict__ Xhi,
                                                     const ushort* __restrict__ Xlo,
                                                     const ushort* __restrict__ Whi,
                                                     const ushort* __restrict__ Wlo,
                                                     const float* __restrict__ Bv,
                                                     float* __restrict__ H, int M)
{
    const int tid = threadIdx.x;
    const int wid = tid >> 6, lane = tid & 63;
    const int wr = wid >> 1, wc = wid & 1;
    const int rowbase = blockIdx.x * 64 + wr * 32;
    const int colbase = wc * 64;
    const int lr = lane & 15, lk = lane >> 4;

    f32x4 acc[2][4];
    #pragma unroll
    for (int rt = 0; rt < 2; ++rt)
        #pragma unroll
        for (int nt = 0; nt < 4; ++nt) acc[rt][nt] = (f32x4){0.f, 0.f, 0.f, 0.f};

    mfma_main(Xhi, Xlo, Whi, Wlo, rowbase, colbase, lr, lk, acc);

    #pragma unroll
    for (int nt = 0; nt < 4; ++nt) {
        const int col = colbase + nt * 16 + lr;
        const float bv = Bv[col];
        #pragma unroll
        for (int rt = 0; rt < 2; ++rt) {
            #pragma unroll
            for (int r = 0; r < 4; ++r) {
                int row = rowbase + rt * 16 + lk * 4 + r;
                if (row < M)
                    H[(size_t)row * 128 + col] = fmaxf(acc[rt][nt][r] + bv, 0.f);
            }
        }
    }
}

// ---------------- Layer 1 + classifier, MFMA main loop + LDS-reduced classifier ----------------
__global__ __launch_bounds__(256) void gnn_lin1_mfma(const ushort* __restrict__ Ahi,
                                                     const ushort* __restrict__ Alo,
                                                     const ushort* __restrict__ Whi,
                                                     const ushort* __restrict__ Wlo,
                                                     const float* __restrict__ Bv,
                                                     const float* __restrict__ Wc,
                                                     const float* __restrict__ bc,
                                                     float* __restrict__ Out, int M)
{
    __shared__ float red[256 * 33];

    const int tid = threadIdx.x;
    const int wid = tid >> 6, lane = tid & 63;
    const int wr = wid >> 1, wc = wid & 1;
    const int rowbase = blockIdx.x * 64 + wr * 32;
    const int colbase = wc * 64;
    const int lr = lane & 15, lk = lane >> 4;

    f32x4 acc[2][4];
    #pragma unroll
    for (int rt = 0; rt < 2; ++rt)
        #pragma unroll
        for (int nt = 0; nt < 4; ++nt) acc[rt][nt] = (f32x4){0.f, 0.f, 0.f, 0.f};

    mfma_main(Ahi, Alo, Whi, Wlo, rowbase, colbase, lr, lk, acc);

    // h2 = relu(acc + b1); classifier partials over this lane's 4 cols (one per nt)
    f32x4 p[2][4];   // [rt][reg] over 4 classes
    #pragma unroll
    for (int rt = 0; rt < 2; ++rt)
        #pragma unroll
        for (int r = 0; r < 4; ++r) p[rt][r] = (f32x4){0.f, 0.f, 0.f, 0.f};

    #pragma unroll
    for (int nt = 0; nt < 4; ++nt) {
        const int col = colbase + nt * 16 + lr;
        const float bv = Bv[col];
        f32x4 wcv = { Wc[col], Wc[128 + col], Wc[256 + col], Wc[384 + col] };
        #pragma unroll
        for (int rt = 0; rt < 2; ++rt)
            #pragma unroll
            for (int r = 0; r < 4; ++r) {
                float h2 = fmaxf(acc[rt][nt][r] + bv, 0.f);
                p[rt][r] += wcv * h2;
            }
    }

    // stash partials: red[tid*33 + rt*16 + reg*4 + cls]  (stride 33 => bank-conflict-free)
    #pragma unroll
    for (int rt = 0; rt < 2; ++rt)
        #pragma unroll
        for (int r = 0; r < 4; ++r)
            #pragma unroll
            for (int c = 0; c < 4; ++c)
                red[tid * 33 + rt * 16 + r * 4 + c] = p[rt][r][c];
    __syncthreads();

    // one thread per (row_local, cls): sum over 2 col-halves x 16 lanes
    const int row_local = tid >> 2, cls = tid & 3;
    const int wr2 = row_local >> 5, rt2 = (row_local >> 4) & 1;
    const int lg = (row_local >> 2) & 3, reg = row_local & 3;
    float s = bc[cls];
    #pragma unroll
    for (int w2 = 0; w2 < 2; ++w2)
        #pragma unroll
        for (int i = 0; i < 16; ++i) {
            int lane_lin = (wr2 * 2 + w2) * 64 + lg * 16 + i;
            s += red[lane_lin * 33 + rt2 * 16 + reg * 4 + cls];
        }
    int row = blockIdx.x * 64 + row_local;
    if (row < M) Out[(size_t)row * 4 + cls] = s;
}

// ---------------- CSR build ----------------
__global__ __launch_bounds__(256) void count_deg(const int* __restrict__ rows,
                                                 int* __restrict__ deg, int E)
{
    int e = blockIdx.x * 256 + threadIdx.x;
    if (e < E) atomicAdd(&deg[rows[e]], 1);
}

__global__ __launch_bounds__(256) void scan_blocks(const int* __restrict__ deg,
                                                   int* __restrict__ off,
                                                   int* __restrict__ bsum, int M)
{
    __shared__ int sh[256];
    int i = blockIdx.x * 256 + threadIdx.x;
    int v = (i < M) ? deg[i] : 0;
    sh[threadIdx.x] = v;
    __syncthreads();
    #pragma unroll
    for (int d = 1; d < 256; d <<= 1) {
        int t = (threadIdx.x >= d) ? sh[threadIdx.x - d] : 0;
        __syncthreads();
        sh[threadIdx.x] += t;
        __syncthreads();
    }
    if (i < M) off[i] = sh[threadIdx.x] - v;
    if (threadIdx.x == 255) bsum[blockIdx.x] = sh[255];
}

__global__ __launch_bounds__(512) void scan_bsum(int* __restrict__ bsum, int NB)
{
    __shared__ int sh[512];
    int v = (threadIdx.x < NB) ? bsum[threadIdx.x] : 0;
    sh[threadIdx.x] = v;
    __syncthreads();
    #pragma unroll
    for (int d = 1; d < 512; d <<= 1) {
        int t = (threadIdx.x >= d) ? sh[threadIdx.x - d] : 0;
        __syncthreads();
        sh[threadIdx.x] += t;
        __syncthreads();
    }
    if (threadIdx.x < NB) bsum[threadIdx.x] = sh[threadIdx.x] - v;
}

__global__ __launch_bounds__(256) void add_off(int* __restrict__ off,
                                               const int* __restrict__ bsum,
                                               int* __restrict__ pos, int M)
{
    int i = blockIdx.x * 256 + threadIdx.x;
    if (i < M) {
        int o = off[i] + bsum[i >> 8];
        off[i] = o;
        pos[i] = o;
    }
}

__global__ __launch_bounds__(256) void fill_csr(const int* __restrict__ rows,
                                                const int* __restrict__ cols,
                                                int* __restrict__ pos,
                                                int* __restrict__ col_sorted, int E)
{
    int e = blockIdx.x * 256 + threadIdx.x;
    if (e < E) {
        int p = atomicAdd(&pos[rows[e]], 1);
        col_sorted[p] = cols[e];
    }
}

// ---------------- Aggregation: agg = h + gather-sum/deg, emitted as bf16 hi/lo ----------------
__global__ __launch_bounds__(256) void gnn_aggregate(const float* __restrict__ H,
                                                     const int* __restrict__ off,
                                                     const int* __restrict__ deg,
                                                     const int* __restrict__ col_sorted,
                                                     ushort* __restrict__ AggHi,
                                                     ushort* __restrict__ AggLo,
                                                     int M, int Mpad)
{
    int gid  = blockIdx.x * 8 + (threadIdx.x >> 5);
    int lane = threadIdx.x & 31;
    if (gid >= Mpad) return;
    size_t oidx = (size_t)gid * 32 + lane;   // ushort4 index
    if (gid >= M) {
        ((ushort4*)AggHi)[oidx] = make_ushort4(0, 0, 0, 0);
        ((ushort4*)AggLo)[oidx] = make_ushort4(0, 0, 0, 0);
        return;
    }

    const float4* H4 = (const float4*)H;
    int start = off[gid];
    int d     = deg[gid];

    float4 acc = make_float4(0.f, 0.f, 0.f, 0.f);
    for (int e = start; e < start + d; ++e) {
        int c = col_sorted[e];
        float4 v = H4[(size_t)c * 32 + lane];
        acc.x += v.x; acc.y += v.y; acc.z += v.z; acc.w += v.w;
    }
    float inv = 1.0f / fmaxf((float)d, 1.0f);
    float4 hv = H4[(size_t)gid * 32 + lane];
    float o0 = hv.x + acc.x * inv;
    float o1 = hv.y + acc.y * inv;
    float o2 = hv.z + acc.z * inv;
    float o3 = hv.w + acc.w * inv;

    ushort4 h4, l4;
    h4.x = f2bf(o0); l4.x = f2bf(o0 - bf2f(h4.x));
    h4.y = f2bf(o1); l4.y = f2bf(o1 - bf2f(h4.y));
    h4.z = f2bf(o2); l4.z = f2bf(o2 - bf2f(h4.z));
    h4.w = f2bf(o3); l4.w = f2bf(o3 - bf2f(h4.w));
    ((ushort4*)AggHi)[oidx] = h4;
    ((ushort4*)AggLo)[oidx] = l4;
}

extern "C" void kernel_launch(void* const* d_in, const int* in_sizes, int n_in,
                              void* d_out, int out_size, void* d_ws, size_t ws_size,
                              hipStream_t stream)
{
    const float* x  = (const float*)d_in[0];
    const int*   ei = (const int*)  d_in[1];
    const float* W0 = (const float*)d_in[2];
    const float* b0 = (const float*)d_in[3];
    const float* W1 = (const float*)d_in[4];
    const float* b1 = (const float*)d_in[5];
    const float* Wc = (const float*)d_in[6];
    const float* bc = (const float*)d_in[7];
    float* out = (float*)d_out;

    const int M    = in_sizes[0] / IN_DIM;   // 100000
    const int E    = in_sizes[1] / 2;        // 800000
    const int Mpad = (M + 63) & ~63;         // 100032
    const int NB   = (M + 255) / 256;        // 391

    // workspace layout
    ushort* Xhi = (ushort*)d_ws;                         // Mpad*128 (reused as AggHi)
    ushort* Xlo = Xhi + (size_t)Mpad * 128;              // Mpad*128 (reused as AggLo)
    float*  H   = (float*)(Xlo + (size_t)Mpad * 128);    // M*128 fp32
    ushort* W0h = (ushort*)(H + (size_t)M * 128);        // 16384 each
    ushort* W0l = W0h + 16384;
    ushort* W1h = W0l + 16384;
    ushort* W1l = W1h + 16384;
    int* deg_i  = (int*)(W1l + 16384);                   // M
    int* off    = deg_i + M;                             // M
    int* pos    = off + M;                               // M
    int* bsum   = pos + M;                               // 512
    int* col_sorted = bsum + 512;                        // E

    const int* rows = ei;
    const int* cols = ei + E;

    hipMemsetAsync(deg_i, 0, (size_t)M * sizeof(int), stream);

    const int n    = M * IN_DIM;
    const int npad = Mpad * IN_DIM;
    const int gridCast = (npad / 4 + 255) / 256;
    const int gridMM   = Mpad / 64;            // 1563
    const int gridE    = (E + 255) / 256;
    const int gridN    = (M + 255) / 256;

    cast_x<<<gridCast, 256, 0, stream>>>(x, Xhi, Xlo, n, npad);
    cast_w<<<128, 256, 0, stream>>>(W0, W1, W0h, W0l, W1h, W1l);
    gnn_lin0_mfma<<<gridMM, 256, 0, stream>>>(Xhi, Xlo, W0h, W0l, b0, H, M);

    count_deg<<<gridE, 256, 0, stream>>>(rows, deg_i, E);
    scan_blocks<<<gridN, 256, 0, stream>>>(deg_i, off, bsum, M);
    scan_bsum<<<1, 512, 0, stream>>>(bsum, NB);
    add_off<<<gridN, 256, 0, stream>>>(off, bsum, pos, M);
    fill_csr<<<gridE, 256, 0, stream>>>(rows, cols, pos, col_sorted, E);

    gnn_aggregate<<<(Mpad + 7) / 8, 256, 0, stream>>>(H, off, deg_i, col_sorted,
                                                      Xhi, Xlo, M, Mpad);
    gnn_lin1_mfma<<<gridMM, 256, 0, stream>>>(Xhi, Xlo, W1h, W1l, b1, Wc, bc, out, M);
}

// Round 4
// 325.590 us; speedup vs baseline: 5.1052x; 1.0924x over previous
//
#include <hip/hip_runtime.h>

#define IN_DIM 128
#define HID    128
#define NCLS   4

typedef __attribute__((ext_vector_type(8))) short bf16x8;
typedef __attribute__((ext_vector_type(4))) float f32x4;

// ---- fp32 -> bf16 hi/lo split helpers (RNE) ----
__device__ inline ushort f2bf(float x) {
    uint u = __builtin_bit_cast(uint, x);
    u += 0x7FFFu + ((u >> 16) & 1u);
    return (ushort)(u >> 16);
}
__device__ inline float bf2f(ushort h) {
    uint u = ((uint)h) << 16;
    return __builtin_bit_cast(float, u);
}

__device__ inline void split8(const float4& x0, const float4& x1, bf16x8& h, bf16x8& l) {
    float v[8] = {x0.x, x0.y, x0.z, x0.w, x1.x, x1.y, x1.z, x1.w};
    #pragma unroll
    for (int j = 0; j < 8; ++j) {
        ushort hh = f2bf(v[j]);
        ushort ll = f2bf(v[j] - bf2f(hh));
        h[j] = (short)hh;
        l[j] = (short)ll;
    }
}

// ---------------- cast W0 and W1 (each 128x128) ----------------
__global__ __launch_bounds__(256) void cast_w(const float* __restrict__ W0,
                                              const float* __restrict__ W1,
                                              ushort* __restrict__ w0h, ushort* __restrict__ w0l,
                                              ushort* __restrict__ w1h, ushort* __restrict__ w1l)
{
    int i = blockIdx.x * 256 + threadIdx.x;     // 0..32767
    float v = (i < 16384) ? W0[i] : W1[i - 16384];
    ushort h = f2bf(v);
    ushort l = f2bf(v - bf2f(h));
    if (i < 16384) { w0h[i] = h; w0l[i] = l; }
    else           { w1h[i - 16384] = h; w1l[i - 16384] = l; }
}

// ---------------- Layer 0: H = relu(X @ W0^T + b0), fused fp32->hi/lo split ----------------
// Block: 256 threads / 4 waves (2x2). Wave: 32 rows x 64 cols as 2x4 tiles of 16x16x32.
__global__ __launch_bounds__(256) void gnn_lin0_mfma(const float* __restrict__ X,
                                                     const ushort* __restrict__ Whi,
                                                     const ushort* __restrict__ Wlo,
                                                     const float* __restrict__ Bv,
                                                     ushort* __restrict__ Hhi,
                                                     ushort* __restrict__ Hlo, int M)
{
    const int tid = threadIdx.x;
    const int wid = tid >> 6, lane = tid & 63;
    const int wr = wid >> 1, wc = wid & 1;
    const int rowbase = blockIdx.x * 64 + wr * 32;
    const int colbase = wc * 64;
    const int lr = lane & 15, lk = lane >> 4;

    f32x4 acc[2][4];
    #pragma unroll
    for (int rt = 0; rt < 2; ++rt)
        #pragma unroll
        for (int nt = 0; nt < 4; ++nt) acc[rt][nt] = (f32x4){0.f, 0.f, 0.f, 0.f};

    const float4* X4 = (const float4*)X;

    #pragma unroll
    for (int kt = 0; kt < 4; ++kt) {
        const int ko = kt * 32 + lk * 8;          // k offset of this lane's 8 elems
        bf16x8 ah[2], al[2];
        #pragma unroll
        for (int rt = 0; rt < 2; ++rt) {
            int row = rowbase + rt * 16 + lr;
            float4 x0 = make_float4(0.f, 0.f, 0.f, 0.f);
            float4 x1 = x0;
            if (row < M) {
                size_t base = (size_t)row * 32 + (ko >> 2);
                x0 = X4[base];
                x1 = X4[base + 1];
            }
            split8(x0, x1, ah[rt], al[rt]);
        }
        #pragma unroll
        for (int nt = 0; nt < 4; ++nt) {
            size_t bo = (size_t)(colbase + nt * 16 + lr) * 128 + ko;
            bf16x8 bh = *(const bf16x8*)(Whi + bo);
            bf16x8 bl = *(const bf16x8*)(Wlo + bo);
            #pragma unroll
            for (int rt = 0; rt < 2; ++rt) {
                acc[rt][nt] = __builtin_amdgcn_mfma_f32_16x16x32_bf16(ah[rt], bh, acc[rt][nt], 0, 0, 0);
                acc[rt][nt] = __builtin_amdgcn_mfma_f32_16x16x32_bf16(ah[rt], bl, acc[rt][nt], 0, 0, 0);
                acc[rt][nt] = __builtin_amdgcn_mfma_f32_16x16x32_bf16(al[rt], bh, acc[rt][nt], 0, 0, 0);
            }
        }
    }

    #pragma unroll
    for (int nt = 0; nt < 4; ++nt) {
        const int col = colbase + nt * 16 + lr;
        const float bv = Bv[col];
        #pragma unroll
        for (int rt = 0; rt < 2; ++rt) {
            #pragma unroll
            for (int r = 0; r < 4; ++r) {
                int row = rowbase + rt * 16 + lk * 4 + r;
                if (row < M) {
                    float o = fmaxf(acc[rt][nt][r] + bv, 0.f);
                    ushort hh = f2bf(o);
                    ushort ll = f2bf(o - bf2f(hh));
                    size_t oo = (size_t)row * 128 + col;
                    Hhi[oo] = hh;
                    Hlo[oo] = ll;
                }
            }
        }
    }
}

// ---------------- Layer 1 + classifier: A from bf16 hi/lo planes ----------------
__global__ __launch_bounds__(256) void gnn_lin1_mfma(const ushort* __restrict__ Ahi,
                                                     const ushort* __restrict__ Alo,
                                                     const ushort* __restrict__ Whi,
                                                     const ushort* __restrict__ Wlo,
                                                     const float* __restrict__ Bv,
                                                     const float* __restrict__ Wc,
                                                     const float* __restrict__ bc,
                                                     float* __restrict__ Out, int M)
{
    __shared__ float red[256 * 33];

    const int tid = threadIdx.x;
    const int wid = tid >> 6, lane = tid & 63;
    const int wr = wid >> 1, wc = wid & 1;
    const int rowbase = blockIdx.x * 64 + wr * 32;
    const int colbase = wc * 64;
    const int lr = lane & 15, lk = lane >> 4;

    f32x4 acc[2][4];
    #pragma unroll
    for (int rt = 0; rt < 2; ++rt)
        #pragma unroll
        for (int nt = 0; nt < 4; ++nt) acc[rt][nt] = (f32x4){0.f, 0.f, 0.f, 0.f};

    #pragma unroll
    for (int kt = 0; kt < 4; ++kt) {
        const int ko = kt * 32 + lk * 8;
        bf16x8 ah[2], al[2];
        #pragma unroll
        for (int rt = 0; rt < 2; ++rt) {
            size_t ao = (size_t)(rowbase + rt * 16 + lr) * 128 + ko;
            ah[rt] = *(const bf16x8*)(Ahi + ao);
            al[rt] = *(const bf16x8*)(Alo + ao);
        }
        #pragma unroll
        for (int nt = 0; nt < 4; ++nt) {
            size_t bo = (size_t)(colbase + nt * 16 + lr) * 128 + ko;
            bf16x8 bh = *(const bf16x8*)(Whi + bo);
            bf16x8 bl = *(const bf16x8*)(Wlo + bo);
            #pragma unroll
            for (int rt = 0; rt < 2; ++rt) {
                acc[rt][nt] = __builtin_amdgcn_mfma_f32_16x16x32_bf16(ah[rt], bh, acc[rt][nt], 0, 0, 0);
                acc[rt][nt] = __builtin_amdgcn_mfma_f32_16x16x32_bf16(ah[rt], bl, acc[rt][nt], 0, 0, 0);
                acc[rt][nt] = __builtin_amdgcn_mfma_f32_16x16x32_bf16(al[rt], bh, acc[rt][nt], 0, 0, 0);
            }
        }
    }

    // h2 = relu(acc + b1); classifier partials over this lane's cols
    f32x4 p[2][4];   // [rt][reg] -> 4 classes
    #pragma unroll
    for (int rt = 0; rt < 2; ++rt)
        #pragma unroll
        for (int r = 0; r < 4; ++r) p[rt][r] = (f32x4){0.f, 0.f, 0.f, 0.f};

    #pragma unroll
    for (int nt = 0; nt < 4; ++nt) {
        const int col = colbase + nt * 16 + lr;
        const float bv = Bv[col];
        f32x4 wcv = { Wc[col], Wc[128 + col], Wc[256 + col], Wc[384 + col] };
        #pragma unroll
        for (int rt = 0; rt < 2; ++rt)
            #pragma unroll
            for (int r = 0; r < 4; ++r) {
                float h2 = fmaxf(acc[rt][nt][r] + bv, 0.f);
                p[rt][r] += wcv * h2;
            }
    }

    #pragma unroll
    for (int rt = 0; rt < 2; ++rt)
        #pragma unroll
        for (int r = 0; r < 4; ++r)
            #pragma unroll
            for (int c = 0; c < 4; ++c)
                red[tid * 33 + rt * 16 + r * 4 + c] = p[rt][r][c];
    __syncthreads();

    const int row_local = tid >> 2, cls = tid & 3;
    const int wr2 = row_local >> 5, rt2 = (row_local >> 4) & 1;
    const int lg = (row_local >> 2) & 3, reg = row_local & 3;
    float s = bc[cls];
    #pragma unroll
    for (int w2 = 0; w2 < 2; ++w2)
        #pragma unroll
        for (int i = 0; i < 16; ++i) {
            int lane_lin = (wr2 * 2 + w2) * 64 + lg * 16 + i;
            s += red[lane_lin * 33 + rt2 * 16 + reg * 4 + cls];
        }
    int row = blockIdx.x * 64 + row_local;
    if (row < M) Out[(size_t)row * 4 + cls] = s;
}

// ---------------- CSR build ----------------
__global__ __launch_bounds__(256) void count_deg(const int* __restrict__ rows,
                                                 int* __restrict__ deg, int E)
{
    int e = blockIdx.x * 256 + threadIdx.x;
    if (e < E) atomicAdd(&deg[rows[e]], 1);
}

__global__ __launch_bounds__(256) void scan_blocks(const int* __restrict__ deg,
                                                   int* __restrict__ off,
                                                   int* __restrict__ bsum, int M)
{
    __shared__ int sh[256];
    int i = blockIdx.x * 256 + threadIdx.x;
    int v = (i < M) ? deg[i] : 0;
    sh[threadIdx.x] = v;
    __syncthreads();
    #pragma unroll
    for (int d = 1; d < 256; d <<= 1) {
        int t = (threadIdx.x >= d) ? sh[threadIdx.x - d] : 0;
        __syncthreads();
        sh[threadIdx.x] += t;
        __syncthreads();
    }
    if (i < M) off[i] = sh[threadIdx.x] - v;
    if (threadIdx.x == 255) bsum[blockIdx.x] = sh[255];
}

__global__ __launch_bounds__(512) void scan_bsum(int* __restrict__ bsum, int NB)
{
    __shared__ int sh[512];
    int v = (threadIdx.x < NB) ? bsum[threadIdx.x] : 0;
    sh[threadIdx.x] = v;
    __syncthreads();
    #pragma unroll
    for (int d = 1; d < 512; d <<= 1) {
        int t = (threadIdx.x >= d) ? sh[threadIdx.x - d] : 0;
        __syncthreads();
        sh[threadIdx.x] += t;
        __syncthreads();
    }
    if (threadIdx.x < NB) bsum[threadIdx.x] = sh[threadIdx.x] - v;
}

__global__ __launch_bounds__(256) void add_off(int* __restrict__ off,
                                               const int* __restrict__ bsum,
                                               int* __restrict__ pos, int M)
{
    int i = blockIdx.x * 256 + threadIdx.x;
    if (i < M) {
        int o = off[i] + bsum[i >> 8];
        off[i] = o;
        pos[i] = o;
    }
}

__global__ __launch_bounds__(256) void fill_csr(const int* __restrict__ rows,
                                                const int* __restrict__ cols,
                                                int* __restrict__ pos,
                                                int* __restrict__ col_sorted, int E)
{
    int e = blockIdx.x * 256 + threadIdx.x;
    if (e < E) {
        int p = atomicAdd(&pos[rows[e]], 1);
        col_sorted[p] = cols[e];
    }
}

// ---------------- Aggregation ----------------
// in = h + gather_sum(h_bf16hi)/max(deg,1); emitted as bf16 hi/lo planes.
// One 32-lane group per node; lane owns 4 channels (ushort4 of hi plane = 8 B).
__global__ __launch_bounds__(256) void gnn_aggregate(const ushort* __restrict__ Hhi,
                                                     const ushort* __restrict__ Hlo,
                                                     const int* __restrict__ off,
                                                     const int* __restrict__ deg,
                                                     const int* __restrict__ col_sorted,
                                                     ushort* __restrict__ InHi,
                                                     ushort* __restrict__ InLo,
                                                     int M, int Mpad)
{
    int gid  = blockIdx.x * 8 + (threadIdx.x >> 5);
    int lane = threadIdx.x & 31;
    if (gid >= Mpad) return;
    size_t oidx = (size_t)gid * 32 + lane;   // ushort4 index
    if (gid >= M) {
        ((ushort4*)InHi)[oidx] = make_ushort4(0, 0, 0, 0);
        ((ushort4*)InLo)[oidx] = make_ushort4(0, 0, 0, 0);
        return;
    }

    const ushort4* G = (const ushort4*)Hhi;
    int start = off[gid];
    int d     = deg[gid];
    int end   = start + d;

    float a0 = 0.f, a1 = 0.f, a2 = 0.f, a3 = 0.f;
    float b0 = 0.f, b1 = 0.f, b2 = 0.f, b3 = 0.f;
    int e = start;
    for (; e + 2 <= end; e += 2) {
        int c0 = col_sorted[e];
        int c1 = col_sorted[e + 1];
        ushort4 g0 = G[(size_t)c0 * 32 + lane];
        ushort4 g1 = G[(size_t)c1 * 32 + lane];
        a0 += bf2f(g0.x); a1 += bf2f(g0.y); a2 += bf2f(g0.z); a3 += bf2f(g0.w);
        b0 += bf2f(g1.x); b1 += bf2f(g1.y); b2 += bf2f(g1.z); b3 += bf2f(g1.w);
    }
    if (e < end) {
        int c0 = col_sorted[e];
        ushort4 g0 = G[(size_t)c0 * 32 + lane];
        a0 += bf2f(g0.x); a1 += bf2f(g0.y); a2 += bf2f(g0.z); a3 += bf2f(g0.w);
    }
    a0 += b0; a1 += b1; a2 += b2; a3 += b3;

    float inv = 1.0f / fmaxf((float)d, 1.0f);
    ushort4 rh = ((const ushort4*)Hhi)[oidx];
    ushort4 rl = ((const ushort4*)Hlo)[oidx];
    float o0 = bf2f(rh.x) + bf2f(rl.x) + a0 * inv;
    float o1 = bf2f(rh.y) + bf2f(rl.y) + a1 * inv;
    float o2 = bf2f(rh.z) + bf2f(rl.z) + a2 * inv;
    float o3 = bf2f(rh.w) + bf2f(rl.w) + a3 * inv;

    ushort4 h4, l4;
    h4.x = f2bf(o0); l4.x = f2bf(o0 - bf2f(h4.x));
    h4.y = f2bf(o1); l4.y = f2bf(o1 - bf2f(h4.y));
    h4.z = f2bf(o2); l4.z = f2bf(o2 - bf2f(h4.z));
    h4.w = f2bf(o3); l4.w = f2bf(o3 - bf2f(h4.w));
    ((ushort4*)InHi)[oidx] = h4;
    ((ushort4*)InLo)[oidx] = l4;
}

extern "C" void kernel_launch(void* const* d_in, const int* in_sizes, int n_in,
                              void* d_out, int out_size, void* d_ws, size_t ws_size,
                              hipStream_t stream)
{
    const float* x  = (const float*)d_in[0];
    const int*   ei = (const int*)  d_in[1];
    const float* W0 = (const float*)d_in[2];
    const float* b0 = (const float*)d_in[3];
    const float* W1 = (const float*)d_in[4];
    const float* b1 = (const float*)d_in[5];
    const float* Wc = (const float*)d_in[6];
    const float* bc = (const float*)d_in[7];
    float* out = (float*)d_out;

    const int M    = in_sizes[0] / IN_DIM;   // 100000
    const int E    = in_sizes[1] / 2;        // 800000
    const int Mpad = (M + 63) & ~63;         // 100032
    const int NB   = (M + 255) / 256;        // 391

    // workspace layout
    ushort* Hhi  = (ushort*)d_ws;                        // Mpad*128
    ushort* Hlo  = Hhi  + (size_t)Mpad * 128;
    ushort* InHi = Hlo  + (size_t)Mpad * 128;
    ushort* InLo = InHi + (size_t)Mpad * 128;
    ushort* W0h  = InLo + (size_t)Mpad * 128;            // 16384 each
    ushort* W0l  = W0h + 16384;
    ushort* W1h  = W0l + 16384;
    ushort* W1l  = W1h + 16384;
    int* deg_i   = (int*)(W1l + 16384);                  // M
    int* off     = deg_i + M;                            // M
    int* pos     = off + M;                              // M
    int* bsum    = pos + M;                              // 512
    int* col_sorted = bsum + 512;                        // E

    const int* rows = ei;
    const int* cols = ei + E;

    hipMemsetAsync(deg_i, 0, (size_t)M * sizeof(int), stream);

    const int gridMM = Mpad / 64;            // 1563
    const int gridE  = (E + 255) / 256;
    const int gridN  = (M + 255) / 256;

    cast_w<<<128, 256, 0, stream>>>(W0, W1, W0h, W0l, W1h, W1l);
    gnn_lin0_mfma<<<gridMM, 256, 0, stream>>>(x, W0h, W0l, b0, Hhi, Hlo, M);

    count_deg<<<gridE, 256, 0, stream>>>(rows, deg_i, E);
    scan_blocks<<<gridN, 256, 0, stream>>>(deg_i, off, bsum, M);
    scan_bsum<<<1, 512, 0, stream>>>(bsum, NB);
    add_off<<<gridN, 256, 0, stream>>>(off, bsum, pos, M);
    fill_csr<<<gridE, 256, 0, stream>>>(rows, cols, pos, col_sorted, E);

    gnn_aggregate<<<(Mpad + 7) / 8, 256, 0, stream>>>(Hhi, Hlo, off, deg_i, col_sorted,
                                                      InHi, InLo, M, Mpad);
    gnn_lin1_mfma<<<gridMM, 256, 0, stream>>>(InHi, InLo, W1h, W1l, b1, Wc, bc, out, M);
}

// Round 5
// 319.840 us; speedup vs baseline: 5.1970x; 1.0180x over previous
//
#include <hip/hip_runtime.h>

#define IN_DIM 128
#define HID    128
#define NCLS   4

typedef __attribute__((ext_vector_type(8))) short bf16x8;
typedef __attribute__((ext_vector_type(4))) float f32x4;

// ---- fp32 -> bf16 hi/lo split helpers (RNE) ----
__device__ inline ushort f2bf(float x) {
    uint u = __builtin_bit_cast(uint, x);
    u += 0x7FFFu + ((u >> 16) & 1u);
    return (ushort)(u >> 16);
}
__device__ inline float bf2f(ushort h) {
    uint u = ((uint)h) << 16;
    return __builtin_bit_cast(float, u);
}

__device__ inline void split8(const float4& x0, const float4& x1, bf16x8& h, bf16x8& l) {
    float v[8] = {x0.x, x0.y, x0.z, x0.w, x1.x, x1.y, x1.z, x1.w};
    #pragma unroll
    for (int j = 0; j < 8; ++j) {
        ushort hh = f2bf(v[j]);
        ushort ll = f2bf(v[j] - bf2f(hh));
        h[j] = (short)hh;
        l[j] = (short)ll;
    }
}

// ---------------- cast W0 and W1 (each 128x128) ----------------
__global__ __launch_bounds__(256) void cast_w(const float* __restrict__ W0,
                                              const float* __restrict__ W1,
                                              ushort* __restrict__ w0h, ushort* __restrict__ w0l,
                                              ushort* __restrict__ w1h, ushort* __restrict__ w1l)
{
    int i = blockIdx.x * 256 + threadIdx.x;     // 0..32767
    float v = (i < 16384) ? W0[i] : W1[i - 16384];
    ushort h = f2bf(v);
    ushort l = f2bf(v - bf2f(h));
    if (i < 16384) { w0h[i] = h; w0l[i] = l; }
    else           { w1h[i - 16384] = h; w1l[i - 16384] = l; }
}

// ---------------- Layer 0: H = relu(X @ W0^T + b0), OPERAND-SWAPPED MFMA ----------------
// mfma(A=W-frag, B=X-frag): D "row" (lk*4+reg) = H col, D "col" (lane&15) = H row.
// Wave (wr,wc): 32 rows x 64 cols. acc[nt][rt]: lane owns H[rowbase+rt*16+lr][colbase+nt*16+lk*4 +0..3].
__global__ __launch_bounds__(256) void gnn_lin0_mfma(const float* __restrict__ X,
                                                     const ushort* __restrict__ Whi,
                                                     const ushort* __restrict__ Wlo,
                                                     const float* __restrict__ Bv,
                                                     ushort* __restrict__ Hhi,
                                                     ushort* __restrict__ Hlo, int M)
{
    const int tid = threadIdx.x;
    const int wid = tid >> 6, lane = tid & 63;
    const int wr = wid >> 1, wc = wid & 1;
    const int rowbase = blockIdx.x * 64 + wr * 32;
    const int colbase = wc * 64;
    const int lr = lane & 15, lk = lane >> 4;

    f32x4 acc[4][2];   // [nt][rt]
    #pragma unroll
    for (int nt = 0; nt < 4; ++nt)
        #pragma unroll
        for (int rt = 0; rt < 2; ++rt) acc[nt][rt] = (f32x4){0.f, 0.f, 0.f, 0.f};

    const float4* X4 = (const float4*)X;

    #pragma unroll
    for (int kt = 0; kt < 4; ++kt) {
        const int ko = kt * 32 + lk * 8;
        bf16x8 xh[2], xl[2];
        #pragma unroll
        for (int rt = 0; rt < 2; ++rt) {
            int row = rowbase + rt * 16 + lr;
            float4 x0 = make_float4(0.f, 0.f, 0.f, 0.f);
            float4 x1 = x0;
            if (row < M) {
                size_t base = (size_t)row * 32 + (ko >> 2);
                x0 = X4[base];
                x1 = X4[base + 1];
            }
            split8(x0, x1, xh[rt], xl[rt]);
        }
        #pragma unroll
        for (int nt = 0; nt < 4; ++nt) {
            size_t bo = (size_t)(colbase + nt * 16 + lr) * 128 + ko;
            bf16x8 wh = *(const bf16x8*)(Whi + bo);
            bf16x8 wl = *(const bf16x8*)(Wlo + bo);
            #pragma unroll
            for (int rt = 0; rt < 2; ++rt) {
                acc[nt][rt] = __builtin_amdgcn_mfma_f32_16x16x32_bf16(wh, xh[rt], acc[nt][rt], 0, 0, 0);
                acc[nt][rt] = __builtin_amdgcn_mfma_f32_16x16x32_bf16(wh, xl[rt], acc[nt][rt], 0, 0, 0);
                acc[nt][rt] = __builtin_amdgcn_mfma_f32_16x16x32_bf16(wl, xh[rt], acc[nt][rt], 0, 0, 0);
            }
        }
    }

    // Epilogue: vectorized ushort4 stores (rows < Mpad always valid in workspace)
    #pragma unroll
    for (int nt = 0; nt < 4; ++nt) {
        const int col0 = colbase + nt * 16 + lk * 4;
        const float4 bv4 = *(const float4*)(Bv + col0);
        const float bvv[4] = {bv4.x, bv4.y, bv4.z, bv4.w};
        #pragma unroll
        for (int rt = 0; rt < 2; ++rt) {
            int row = rowbase + rt * 16 + lr;
            ushort4 h4, l4;
            float o0 = fmaxf(acc[nt][rt][0] + bvv[0], 0.f);
            float o1 = fmaxf(acc[nt][rt][1] + bvv[1], 0.f);
            float o2 = fmaxf(acc[nt][rt][2] + bvv[2], 0.f);
            float o3 = fmaxf(acc[nt][rt][3] + bvv[3], 0.f);
            h4.x = f2bf(o0); l4.x = f2bf(o0 - bf2f(h4.x));
            h4.y = f2bf(o1); l4.y = f2bf(o1 - bf2f(h4.y));
            h4.z = f2bf(o2); l4.z = f2bf(o2 - bf2f(h4.z));
            h4.w = f2bf(o3); l4.w = f2bf(o3 - bf2f(h4.w));
            size_t oo = (size_t)row * 128 + col0;
            *(ushort4*)(Hhi + oo) = h4;
            *(ushort4*)(Hlo + oo) = l4;
        }
    }
}

// ---------------- Layer 1 + classifier, operand-swapped ----------------
__global__ __launch_bounds__(256) void gnn_lin1_mfma(const ushort* __restrict__ Ahi,
                                                     const ushort* __restrict__ Alo,
                                                     const ushort* __restrict__ Whi,
                                                     const ushort* __restrict__ Wlo,
                                                     const float* __restrict__ Bv,
                                                     const float* __restrict__ Wc,
                                                     const float* __restrict__ bc,
                                                     float* __restrict__ Out, int M)
{
    __shared__ float red[2][64][4];

    const int tid = threadIdx.x;
    const int wid = tid >> 6, lane = tid & 63;
    const int wr = wid >> 1, wc = wid & 1;
    const int rowbase = blockIdx.x * 64 + wr * 32;
    const int colbase = wc * 64;
    const int lr = lane & 15, lk = lane >> 4;

    f32x4 acc[4][2];
    #pragma unroll
    for (int nt = 0; nt < 4; ++nt)
        #pragma unroll
        for (int rt = 0; rt < 2; ++rt) acc[nt][rt] = (f32x4){0.f, 0.f, 0.f, 0.f};

    #pragma unroll
    for (int kt = 0; kt < 4; ++kt) {
        const int ko = kt * 32 + lk * 8;
        bf16x8 xh[2], xl[2];
        #pragma unroll
        for (int rt = 0; rt < 2; ++rt) {
            size_t ao = (size_t)(rowbase + rt * 16 + lr) * 128 + ko;   // rows < Mpad, zero-padded
            xh[rt] = *(const bf16x8*)(Ahi + ao);
            xl[rt] = *(const bf16x8*)(Alo + ao);
        }
        #pragma unroll
        for (int nt = 0; nt < 4; ++nt) {
            size_t bo = (size_t)(colbase + nt * 16 + lr) * 128 + ko;
            bf16x8 wh = *(const bf16x8*)(Whi + bo);
            bf16x8 wl = *(const bf16x8*)(Wlo + bo);
            #pragma unroll
            for (int rt = 0; rt < 2; ++rt) {
                acc[nt][rt] = __builtin_amdgcn_mfma_f32_16x16x32_bf16(wh, xh[rt], acc[nt][rt], 0, 0, 0);
                acc[nt][rt] = __builtin_amdgcn_mfma_f32_16x16x32_bf16(wh, xl[rt], acc[nt][rt], 0, 0, 0);
                acc[nt][rt] = __builtin_amdgcn_mfma_f32_16x16x32_bf16(wl, xh[rt], acc[nt][rt], 0, 0, 0);
            }
        }
    }

    // h2 = relu(acc + b1); per-lane classifier partial over its 16 cols
    float p[2][4] = {{0.f, 0.f, 0.f, 0.f}, {0.f, 0.f, 0.f, 0.f}};
    #pragma unroll
    for (int nt = 0; nt < 4; ++nt) {
        const int col0 = colbase + nt * 16 + lk * 4;
        const float4 bv4 = *(const float4*)(Bv + col0);
        const float bvv[4] = {bv4.x, bv4.y, bv4.z, bv4.w};
        float4 wcr[4];
        #pragma unroll
        for (int c = 0; c < 4; ++c) wcr[c] = *(const float4*)(Wc + c * HID + col0);
        #pragma unroll
        for (int rt = 0; rt < 2; ++rt) {
            float h2v[4];
            #pragma unroll
            for (int r = 0; r < 4; ++r) h2v[r] = fmaxf(acc[nt][rt][r] + bvv[r], 0.f);
            #pragma unroll
            for (int c = 0; c < 4; ++c) {
                const float* w = (const float*)&wcr[c];
                p[rt][c] = fmaf(h2v[0], w[0], p[rt][c]);
                p[rt][c] = fmaf(h2v[1], w[1], p[rt][c]);
                p[rt][c] = fmaf(h2v[2], w[2], p[rt][c]);
                p[rt][c] = fmaf(h2v[3], w[3], p[rt][c]);
            }
        }
    }
    // reduce across the 4 lane-groups holding the same row (lanes ^16, ^32)
    #pragma unroll
    for (int off = 16; off < 64; off <<= 1)
        #pragma unroll
        for (int rt = 0; rt < 2; ++rt)
            #pragma unroll
            for (int c = 0; c < 4; ++c)
                p[rt][c] += __shfl_xor(p[rt][c], off);

    if (lk == 0) {
        #pragma unroll
        for (int rt = 0; rt < 2; ++rt) {
            f32x4 v = {p[rt][0], p[rt][1], p[rt][2], p[rt][3]};
            *(f32x4*)&red[wc][wr * 32 + rt * 16 + lr][0] = v;
        }
    }
    __syncthreads();

    const int row_local = tid >> 2, cls = tid & 3;
    int row = blockIdx.x * 64 + row_local;
    if (row < M) {
        float s = bc[cls] + red[0][row_local][cls] + red[1][row_local][cls];
        Out[(size_t)row * 4 + cls] = s;
    }
}

// ---------------- CSR build ----------------
__global__ __launch_bounds__(256) void count_deg(const int* __restrict__ rows,
                                                 int* __restrict__ deg, int E)
{
    int e = blockIdx.x * 256 + threadIdx.x;
    if (e < E) atomicAdd(&deg[rows[e]], 1);
}

__global__ __launch_bounds__(256) void scan_blocks(const int* __restrict__ deg,
                                                   int* __restrict__ off,
                                                   int* __restrict__ bsum, int M)
{
    __shared__ int sh[256];
    int i = blockIdx.x * 256 + threadIdx.x;
    int v = (i < M) ? deg[i] : 0;
    sh[threadIdx.x] = v;
    __syncthreads();
    #pragma unroll
    for (int d = 1; d < 256; d <<= 1) {
        int t = (threadIdx.x >= d) ? sh[threadIdx.x - d] : 0;
        __syncthreads();
        sh[threadIdx.x] += t;
        __syncthreads();
    }
    if (i < M) off[i] = sh[threadIdx.x] - v;
    if (threadIdx.x == 255) bsum[blockIdx.x] = sh[255];
}

__global__ __launch_bounds__(512) void scan_bsum(int* __restrict__ bsum, int NB)
{
    __shared__ int sh[512];
    int v = (threadIdx.x < NB) ? bsum[threadIdx.x] : 0;
    sh[threadIdx.x] = v;
    __syncthreads();
    #pragma unroll
    for (int d = 1; d < 512; d <<= 1) {
        int t = (threadIdx.x >= d) ? sh[threadIdx.x - d] : 0;
        __syncthreads();
        sh[threadIdx.x] += t;
        __syncthreads();
    }
    if (threadIdx.x < NB) bsum[threadIdx.x] = sh[threadIdx.x] - v;
}

__global__ __launch_bounds__(256) void add_off(int* __restrict__ off,
                                               const int* __restrict__ bsum,
                                               int* __restrict__ pos, int M)
{
    int i = blockIdx.x * 256 + threadIdx.x;
    if (i < M) {
        int o = off[i] + bsum[i >> 8];
        off[i] = o;
        pos[i] = o;
    }
}

__global__ __launch_bounds__(256) void fill_csr(const int* __restrict__ rows,
                                                const int* __restrict__ cols,
                                                int* __restrict__ pos,
                                                int* __restrict__ col_sorted, int E)
{
    int e = blockIdx.x * 256 + threadIdx.x;
    if (e < E) {
        int p = atomicAdd(&pos[rows[e]], 1);
        col_sorted[p] = cols[e];
    }
}

// ---------------- Aggregation ----------------
// in = h + gather_sum(h_bf16hi)/max(deg,1); emitted as bf16 hi/lo planes.
__global__ __launch_bounds__(256) void gnn_aggregate(const ushort* __restrict__ Hhi,
                                                     const ushort* __restrict__ Hlo,
                                                     const int* __restrict__ off,
                                                     const int* __restrict__ deg,
                                                     const int* __restrict__ col_sorted,
                                                     ushort* __restrict__ InHi,
                                                     ushort* __restrict__ InLo,
                                                     int M, int Mpad)
{
    int gid  = blockIdx.x * 8 + (threadIdx.x >> 5);
    int lane = threadIdx.x & 31;
    if (gid >= Mpad) return;
    size_t oidx = (size_t)gid * 32 + lane;   // ushort4 index
    if (gid >= M) {
        ((ushort4*)InHi)[oidx] = make_ushort4(0, 0, 0, 0);
        ((ushort4*)InLo)[oidx] = make_ushort4(0, 0, 0, 0);
        return;
    }

    const ushort4* G = (const ushort4*)Hhi;
    int start = off[gid];
    int d     = deg[gid];
    int end   = start + d;

    float a0 = 0.f, a1 = 0.f, a2 = 0.f, a3 = 0.f;
    float b0 = 0.f, b1 = 0.f, b2 = 0.f, b3 = 0.f;
    int e = start;
    for (; e + 2 <= end; e += 2) {
        int c0 = col_sorted[e];
        int c1 = col_sorted[e + 1];
        ushort4 g0 = G[(size_t)c0 * 32 + lane];
        ushort4 g1 = G[(size_t)c1 * 32 + lane];
        a0 += bf2f(g0.x); a1 += bf2f(g0.y); a2 += bf2f(g0.z); a3 += bf2f(g0.w);
        b0 += bf2f(g1.x); b1 += bf2f(g1.y); b2 += bf2f(g1.z); b3 += bf2f(g1.w);
    }
    if (e < end) {
        int c0 = col_sorted[e];
        ushort4 g0 = G[(size_t)c0 * 32 + lane];
        a0 += bf2f(g0.x); a1 += bf2f(g0.y); a2 += bf2f(g0.z); a3 += bf2f(g0.w);
    }
    a0 += b0; a1 += b1; a2 += b2; a3 += b3;

    float inv = 1.0f / fmaxf((float)d, 1.0f);
    ushort4 rh = ((const ushort4*)Hhi)[oidx];
    ushort4 rl = ((const ushort4*)Hlo)[oidx];
    float o0 = bf2f(rh.x) + bf2f(rl.x) + a0 * inv;
    float o1 = bf2f(rh.y) + bf2f(rl.y) + a1 * inv;
    float o2 = bf2f(rh.z) + bf2f(rl.z) + a2 * inv;
    float o3 = bf2f(rh.w) + bf2f(rl.w) + a3 * inv;

    ushort4 h4, l4;
    h4.x = f2bf(o0); l4.x = f2bf(o0 - bf2f(h4.x));
    h4.y = f2bf(o1); l4.y = f2bf(o1 - bf2f(h4.y));
    h4.z = f2bf(o2); l4.z = f2bf(o2 - bf2f(h4.z));
    h4.w = f2bf(o3); l4.w = f2bf(o3 - bf2f(h4.w));
    ((ushort4*)InHi)[oidx] = h4;
    ((ushort4*)InLo)[oidx] = l4;
}

extern "C" void kernel_launch(void* const* d_in, const int* in_sizes, int n_in,
                              void* d_out, int out_size, void* d_ws, size_t ws_size,
                              hipStream_t stream)
{
    const float* x  = (const float*)d_in[0];
    const int*   ei = (const int*)  d_in[1];
    const float* W0 = (const float*)d_in[2];
    const float* b0 = (const float*)d_in[3];
    const float* W1 = (const float*)d_in[4];
    const float* b1 = (const float*)d_in[5];
    const float* Wc = (const float*)d_in[6];
    const float* bc = (const float*)d_in[7];
    float* out = (float*)d_out;

    const int M    = in_sizes[0] / IN_DIM;   // 100000
    const int E    = in_sizes[1] / 2;        // 800000
    const int Mpad = (M + 63) & ~63;         // 100032
    const int NB   = (M + 255) / 256;        // 391

    // workspace layout
    ushort* Hhi  = (ushort*)d_ws;                        // Mpad*128
    ushort* Hlo  = Hhi  + (size_t)Mpad * 128;
    ushort* InHi = Hlo  + (size_t)Mpad * 128;
    ushort* InLo = InHi + (size_t)Mpad * 128;
    ushort* W0h  = InLo + (size_t)Mpad * 128;            // 16384 each
    ushort* W0l  = W0h + 16384;
    ushort* W1h  = W0l + 16384;
    ushort* W1l  = W1h + 16384;
    int* deg_i   = (int*)(W1l + 16384);                  // M
    int* off     = deg_i + M;                            // M
    int* pos     = off + M;                              // M
    int* bsum    = pos + M;                              // 512
    int* col_sorted = bsum + 512;                        // E

    const int* rows = ei;
    const int* cols = ei + E;

    hipMemsetAsync(deg_i, 0, (size_t)M * sizeof(int), stream);

    const int gridMM = Mpad / 64;            // 1563
    const int gridE  = (E + 255) / 256;
    const int gridN  = (M + 255) / 256;

    cast_w<<<128, 256, 0, stream>>>(W0, W1, W0h, W0l, W1h, W1l);
    gnn_lin0_mfma<<<gridMM, 256, 0, stream>>>(x, W0h, W0l, b0, Hhi, Hlo, M);

    count_deg<<<gridE, 256, 0, stream>>>(rows, deg_i, E);
    scan_blocks<<<gridN, 256, 0, stream>>>(deg_i, off, bsum, M);
    scan_bsum<<<1, 512, 0, stream>>>(bsum, NB);
    add_off<<<gridN, 256, 0, stream>>>(off, bsum, pos, M);
    fill_csr<<<gridE, 256, 0, stream>>>(rows, cols, pos, col_sorted, E);

    gnn_aggregate<<<(Mpad + 7) / 8, 256, 0, stream>>>(Hhi, Hlo, off, deg_i, col_sorted,
                                                      InHi, InLo, M, Mpad);
    gnn_lin1_mfma<<<gridMM, 256, 0, stream>>>(InHi, InLo, W1h, W1l, b1, Wc, bc, out, M);
}

// Round 7
// 309.257 us; speedup vs baseline: 5.3748x; 1.0342x over previous
//
#include <hip/hip_runtime.h>

#define IN_DIM 128
#define HID    128
#define NCLS   4

typedef __attribute__((ext_vector_type(8))) short bf16x8;
typedef __attribute__((ext_vector_type(4))) float f32x4;

// ---- fp32 -> bf16 hi/lo split helpers (RNE) ----
__device__ inline ushort f2bf(float x) {
    uint u = __builtin_bit_cast(uint, x);
    u += 0x7FFFu + ((u >> 16) & 1u);
    return (ushort)(u >> 16);
}
__device__ inline float bf2f(ushort h) {
    uint u = ((uint)h) << 16;
    return __builtin_bit_cast(float, u);
}

// async global->LDS, 16B per lane; lptr must be wave-uniform (HW adds lane*16)
__device__ inline void gload_lds16(const void* g, void* l) {
    __builtin_amdgcn_global_load_lds((const __attribute__((address_space(1))) void*)g,
                                     (__attribute__((address_space(3))) void*)l, 16, 0, 0);
}

// ---------------- cast W0 and W1 (each 128x128) ----------------
__global__ __launch_bounds__(256) void cast_w(const float* __restrict__ W0,
                                              const float* __restrict__ W1,
                                              ushort* __restrict__ w0h, ushort* __restrict__ w0l,
                                              ushort* __restrict__ w1h, ushort* __restrict__ w1l)
{
    int i = blockIdx.x * 256 + threadIdx.x;     // 0..32767
    float v = (i < 16384) ? W0[i] : W1[i - 16384];
    ushort h = f2bf(v);
    ushort l = f2bf(v - bf2f(h));
    if (i < 16384) { w0h[i] = h; w0l[i] = l; }
    else           { w1h[i - 16384] = h; w1l[i - 16384] = l; }
}

// LDS tile layout (both GEMMs): [64 rows][16 units of 16B], swizzled unit = u ^ (row&7).
// hi plane at lds[0..16384), lo plane at lds[16384..32768).

// ---------------- Layer 0: H = relu(X @ W0^T + b0) ----------------
// Stage: coalesced fp32 load -> in-reg hi/lo split -> swizzled ds_write.
// MFMA (operand-swapped): D col(lane&15)=H row, D row(lk*4+reg)=H col.
__global__ __launch_bounds__(256) void gnn_lin0_mfma(const float* __restrict__ X,
                                                     const ushort* __restrict__ Whi,
                                                     const ushort* __restrict__ Wlo,
                                                     const float* __restrict__ Bv,
                                                     ushort* __restrict__ Hhi,
                                                     ushort* __restrict__ Hlo, int M)
{
    __shared__ uint4 lds4[2048];                 // 32 KiB
    char* lds = (char*)lds4;

    const int tid = threadIdx.x;
    const int bm  = blockIdx.x * 64;

    // ---- stage 64 rows x 128 k ----
    {
        const int row  = tid >> 2;               // 0..63
        const int seg  = tid & 3;                // which 32-elem chunk of the row
        const int grow = min(bm + row, M - 1);   // clamp: dup row, masked later
        const float4* src = (const float4*)((const char*)X + (size_t)grow * 512 + seg * 128);
        float4 v[8];
        #pragma unroll
        for (int j = 0; j < 8; ++j) v[j] = src[j];

        #pragma unroll
        for (int j = 0; j < 4; ++j) {            // 4 units of 8 elems
            uint hw[4], lw[4];
            #pragma unroll
            for (int q = 0; q < 2; ++q) {
                const float4 f = v[j * 2 + q];
                ushort h0 = f2bf(f.x), h1 = f2bf(f.y), h2 = f2bf(f.z), h3 = f2bf(f.w);
                ushort l0 = f2bf(f.x - bf2f(h0)), l1 = f2bf(f.y - bf2f(h1));
                ushort l2 = f2bf(f.z - bf2f(h2)), l3 = f2bf(f.w - bf2f(h3));
                hw[q * 2]     = (uint)h0 | ((uint)h1 << 16);
                hw[q * 2 + 1] = (uint)h2 | ((uint)h3 << 16);
                lw[q * 2]     = (uint)l0 | ((uint)l1 << 16);
                lw[q * 2 + 1] = (uint)l2 | ((uint)l3 << 16);
            }
            int unit = (seg * 4 + j) ^ (row & 7);
            int off  = row * 256 + unit * 16;
            *(uint4*)(lds + off)         = make_uint4(hw[0], hw[1], hw[2], hw[3]);
            *(uint4*)(lds + 16384 + off) = make_uint4(lw[0], lw[1], lw[2], lw[3]);
        }
    }
    __syncthreads();

    const int wid = tid >> 6, lane = tid & 63;
    const int wr = wid >> 1, wc = wid & 1;
    const int colbase = wc * 64;
    const int lr = lane & 15, lk = lane >> 4;

    f32x4 acc[4][2];
    #pragma unroll
    for (int nt = 0; nt < 4; ++nt)
        #pragma unroll
        for (int rt = 0; rt < 2; ++rt) acc[nt][rt] = (f32x4){0.f, 0.f, 0.f, 0.f};

    #pragma unroll
    for (int kt = 0; kt < 4; ++kt) {
        const int ko = kt * 32 + lk * 8;
        bf16x8 xh[2], xl[2];
        #pragma unroll
        for (int rt = 0; rt < 2; ++rt) {
            int lrow = wr * 32 + rt * 16 + lr;
            int unit = (kt * 4 + lk) ^ (lrow & 7);
            int off  = lrow * 256 + unit * 16;
            xh[rt] = *(const bf16x8*)(lds + off);
            xl[rt] = *(const bf16x8*)(lds + 16384 + off);
        }
        #pragma unroll
        for (int nt = 0; nt < 4; ++nt) {
            size_t bo = (size_t)(colbase + nt * 16 + lr) * 128 + ko;
            bf16x8 wh = *(const bf16x8*)(Whi + bo);
            bf16x8 wl = *(const bf16x8*)(Wlo + bo);
            #pragma unroll
            for (int rt = 0; rt < 2; ++rt) {
                acc[nt][rt] = __builtin_amdgcn_mfma_f32_16x16x32_bf16(wh, xh[rt], acc[nt][rt], 0, 0, 0);
                acc[nt][rt] = __builtin_amdgcn_mfma_f32_16x16x32_bf16(wh, xl[rt], acc[nt][rt], 0, 0, 0);
                acc[nt][rt] = __builtin_amdgcn_mfma_f32_16x16x32_bf16(wl, xh[rt], acc[nt][rt], 0, 0, 0);
            }
        }
    }

    // Epilogue: vectorized ushort4 stores into Mpad-padded workspace (no guard needed)
    #pragma unroll
    for (int nt = 0; nt < 4; ++nt) {
        const int col0 = colbase + nt * 16 + lk * 4;
        const float4 bv4 = *(const float4*)(Bv + col0);
        const float bvv[4] = {bv4.x, bv4.y, bv4.z, bv4.w};
        #pragma unroll
        for (int rt = 0; rt < 2; ++rt) {
            int row = bm + wr * 32 + rt * 16 + lr;
            float o0 = fmaxf(acc[nt][rt][0] + bvv[0], 0.f);
            float o1 = fmaxf(acc[nt][rt][1] + bvv[1], 0.f);
            float o2 = fmaxf(acc[nt][rt][2] + bvv[2], 0.f);
            float o3 = fmaxf(acc[nt][rt][3] + bvv[3], 0.f);
            ushort4 h4, l4;
            h4.x = f2bf(o0); l4.x = f2bf(o0 - bf2f(h4.x));
            h4.y = f2bf(o1); l4.y = f2bf(o1 - bf2f(h4.y));
            h4.z = f2bf(o2); l4.z = f2bf(o2 - bf2f(h4.z));
            h4.w = f2bf(o3); l4.w = f2bf(o3 - bf2f(h4.w));
            size_t oo = (size_t)row * 128 + col0;
            *(ushort4*)(Hhi + oo) = h4;
            *(ushort4*)(Hlo + oo) = l4;
        }
    }
}

// ---------------- Layer 1 + classifier ----------------
// Stage A (already bf16 planes) via global_load_lds with PRE-SWIZZLED global source.
__global__ __launch_bounds__(256) void gnn_lin1_mfma(const ushort* __restrict__ Ahi,
                                                     const ushort* __restrict__ Alo,
                                                     const ushort* __restrict__ Whi,
                                                     const ushort* __restrict__ Wlo,
                                                     const float* __restrict__ Bv,
                                                     const float* __restrict__ Wc,
                                                     const float* __restrict__ bc,
                                                     float* __restrict__ Out, int M)
{
    __shared__ uint4 lds4[2048];                 // 32 KiB
    __shared__ float red[2][64][4];
    char* lds = (char*)lds4;

    const int tid = threadIdx.x;
    const int wid = tid >> 6, lane = tid & 63;
    const int bm  = blockIdx.x * 64;

    // ---- stage: waves 0,1 fill hi plane; waves 2,3 fill lo plane ----
    #pragma unroll
    for (int i = 0; i < 8; ++i) {
        int o = wid * 8192 + i * 1024 + lane * 16;       // linear LDS byte this lane fills
        const ushort* plane = (o < 16384) ? Ahi : Alo;   // wave-uniform select
        int po   = o & 16383;
        int row  = po >> 8;
        int unit = (po >> 4) & 15;
        const char* src = (const char*)plane + (size_t)(bm + row) * 256
                        + ((unit ^ (row & 7)) << 4);     // pre-swizzled source
        gload_lds16(src, lds + wid * 8192 + i * 1024);   // wave-uniform dest
    }
    __syncthreads();

    const int wr = wid >> 1, wc = wid & 1;
    const int colbase = wc * 64;
    const int lr = lane & 15, lk = lane >> 4;

    f32x4 acc[4][2];
    #pragma unroll
    for (int nt = 0; nt < 4; ++nt)
        #pragma unroll
        for (int rt = 0; rt < 2; ++rt) acc[nt][rt] = (f32x4){0.f, 0.f, 0.f, 0.f};

    #pragma unroll
    for (int kt = 0; kt < 4; ++kt) {
        const int ko = kt * 32 + lk * 8;
        bf16x8 xh[2], xl[2];
        #pragma unroll
        for (int rt = 0; rt < 2; ++rt) {
            int lrow = wr * 32 + rt * 16 + lr;
            int unit = (kt * 4 + lk) ^ (lrow & 7);
            int off  = lrow * 256 + unit * 16;
            xh[rt] = *(const bf16x8*)(lds + off);
            xl[rt] = *(const bf16x8*)(lds + 16384 + off);
        }
        #pragma unroll
        for (int nt = 0; nt < 4; ++nt) {
            size_t bo = (size_t)(colbase + nt * 16 + lr) * 128 + ko;
            bf16x8 wh = *(const bf16x8*)(Whi + bo);
            bf16x8 wl = *(const bf16x8*)(Wlo + bo);
            #pragma unroll
            for (int rt = 0; rt < 2; ++rt) {
                acc[nt][rt] = __builtin_amdgcn_mfma_f32_16x16x32_bf16(wh, xh[rt], acc[nt][rt], 0, 0, 0);
                acc[nt][rt] = __builtin_amdgcn_mfma_f32_16x16x32_bf16(wh, xl[rt], acc[nt][rt], 0, 0, 0);
                acc[nt][rt] = __builtin_amdgcn_mfma_f32_16x16x32_bf16(wl, xh[rt], acc[nt][rt], 0, 0, 0);
            }
        }
    }

    // h2 = relu(acc + b1); per-lane classifier partial over its 16 cols
    float p[2][4] = {{0.f, 0.f, 0.f, 0.f}, {0.f, 0.f, 0.f, 0.f}};
    #pragma unroll
    for (int nt = 0; nt < 4; ++nt) {
        const int col0 = colbase + nt * 16 + lk * 4;
        const float4 bv4 = *(const float4*)(Bv + col0);
        const float bvv[4] = {bv4.x, bv4.y, bv4.z, bv4.w};
        float4 wcr[4];
        #pragma unroll
        for (int c = 0; c < 4; ++c) wcr[c] = *(const float4*)(Wc + c * HID + col0);
        #pragma unroll
        for (int rt = 0; rt < 2; ++rt) {
            float h2v[4];
            #pragma unroll
            for (int r = 0; r < 4; ++r) h2v[r] = fmaxf(acc[nt][rt][r] + bvv[r], 0.f);
            #pragma unroll
            for (int c = 0; c < 4; ++c) {
                const float* w = (const float*)&wcr[c];
                p[rt][c] = fmaf(h2v[0], w[0], p[rt][c]);
                p[rt][c] = fmaf(h2v[1], w[1], p[rt][c]);
                p[rt][c] = fmaf(h2v[2], w[2], p[rt][c]);
                p[rt][c] = fmaf(h2v[3], w[3], p[rt][c]);
            }
        }
    }
    #pragma unroll
    for (int off = 16; off < 64; off <<= 1)
        #pragma unroll
        for (int rt = 0; rt < 2; ++rt)
            #pragma unroll
            for (int c = 0; c < 4; ++c)
                p[rt][c] += __shfl_xor(p[rt][c], off);

    if (lk == 0) {
        #pragma unroll
        for (int rt = 0; rt < 2; ++rt) {
            f32x4 v = {p[rt][0], p[rt][1], p[rt][2], p[rt][3]};
            *(f32x4*)&red[wc][wr * 32 + rt * 16 + lr][0] = v;
        }
    }
    __syncthreads();

    const int row_local = tid >> 2, cls = tid & 3;
    int row = blockIdx.x * 64 + row_local;
    if (row < M) {
        float s = bc[cls] + red[0][row_local][cls] + red[1][row_local][cls];
        Out[(size_t)row * 4 + cls] = s;
    }
}

// ---------------- CSR build ----------------
__global__ __launch_bounds__(256) void count_deg(const int* __restrict__ rows,
                                                 int* __restrict__ deg, int E)
{
    int e = blockIdx.x * 256 + threadIdx.x;
    if (e < E) atomicAdd(&deg[rows[e]], 1);
}

__global__ __launch_bounds__(256) void scan_blocks(const int* __restrict__ deg,
                                                   int* __restrict__ off,
                                                   int* __restrict__ bsum, int M)
{
    __shared__ int sh[256];
    int i = blockIdx.x * 256 + threadIdx.x;
    int v = (i < M) ? deg[i] : 0;
    sh[threadIdx.x] = v;
    __syncthreads();
    #pragma unroll
    for (int d = 1; d < 256; d <<= 1) {
        int t = (threadIdx.x >= d) ? sh[threadIdx.x - d] : 0;
        __syncthreads();
        sh[threadIdx.x] += t;
        __syncthreads();
    }
    if (i < M) off[i] = sh[threadIdx.x] - v;
    if (threadIdx.x == 255) bsum[blockIdx.x] = sh[255];
}

__global__ __launch_bounds__(512) void scan_bsum(int* __restrict__ bsum, int NB)
{
    __shared__ int sh[512];
    int v = (threadIdx.x < NB) ? bsum[threadIdx.x] : 0;
    sh[threadIdx.x] = v;
    __syncthreads();
    #pragma unroll
    for (int d = 1; d < 512; d <<= 1) {
        int t = (threadIdx.x >= d) ? sh[threadIdx.x - d] : 0;
        __syncthreads();
        sh[threadIdx.x] += t;
        __syncthreads();
    }
    if (threadIdx.x < NB) bsum[threadIdx.x] = sh[threadIdx.x] - v;
}

__global__ __launch_bounds__(256) void add_off(int* __restrict__ off,
                                               const int* __restrict__ bsum,
                                               int* __restrict__ pos, int M)
{
    int i = blockIdx.x * 256 + threadIdx.x;
    if (i < M) {
        int o = off[i] + bsum[i >> 8];
        off[i] = o;
        pos[i] = o;
    }
}

__global__ __launch_bounds__(256) void fill_csr(const int* __restrict__ rows,
                                                const int* __restrict__ cols,
                                                int* __restrict__ pos,
                                                int* __restrict__ col_sorted, int E)
{
    int e = blockIdx.x * 256 + threadIdx.x;
    if (e < E) {
        int p = atomicAdd(&pos[rows[e]], 1);
        col_sorted[p] = cols[e];
    }
}

// ---------------- Aggregation ----------------
// in = h + gather_sum(h_bf16hi)/max(deg,1); emitted as bf16 hi/lo planes.
__global__ __launch_bounds__(256) void gnn_aggregate(const ushort* __restrict__ Hhi,
                                                     const ushort* __restrict__ Hlo,
                                                     const int* __restrict__ off,
                                                     const int* __restrict__ deg,
                                                     const int* __restrict__ col_sorted,
                                                     ushort* __restrict__ InHi,
                                                     ushort* __restrict__ InLo,
                                                     int M, int Mpad)
{
    int gid  = blockIdx.x * 8 + (threadIdx.x >> 5);
    int lane = threadIdx.x & 31;
    if (gid >= Mpad) return;
    size_t oidx = (size_t)gid * 32 + lane;   // ushort4 index
    if (gid >= M) {
        ((ushort4*)InHi)[oidx] = make_ushort4(0, 0, 0, 0);
        ((ushort4*)InLo)[oidx] = make_ushort4(0, 0, 0, 0);
        return;
    }

    const ushort4* G = (const ushort4*)Hhi;
    int start = off[gid];
    int d     = deg[gid];
    int end   = start + d;

    float s0[4] = {0.f, 0.f, 0.f, 0.f};
    float s1[4] = {0.f, 0.f, 0.f, 0.f};
    float s2[4] = {0.f, 0.f, 0.f, 0.f};
    float s3[4] = {0.f, 0.f, 0.f, 0.f};
    int e = start;
    for (; e + 4 <= end; e += 4) {
        int c0 = col_sorted[e], c1 = col_sorted[e + 1];
        int c2 = col_sorted[e + 2], c3 = col_sorted[e + 3];
        ushort4 g0 = G[(size_t)c0 * 32 + lane];
        ushort4 g1 = G[(size_t)c1 * 32 + lane];
        ushort4 g2 = G[(size_t)c2 * 32 + lane];
        ushort4 g3 = G[(size_t)c3 * 32 + lane];
        s0[0] += bf2f(g0.x); s0[1] += bf2f(g0.y); s0[2] += bf2f(g0.z); s0[3] += bf2f(g0.w);
        s1[0] += bf2f(g1.x); s1[1] += bf2f(g1.y); s1[2] += bf2f(g1.z); s1[3] += bf2f(g1.w);
        s2[0] += bf2f(g2.x); s2[1] += bf2f(g2.y); s2[2] += bf2f(g2.z); s2[3] += bf2f(g2.w);
        s3[0] += bf2f(g3.x); s3[1] += bf2f(g3.y); s3[2] += bf2f(g3.z); s3[3] += bf2f(g3.w);
    }
    for (; e < end; ++e) {
        int c0 = col_sorted[e];
        ushort4 g0 = G[(size_t)c0 * 32 + lane];
        s0[0] += bf2f(g0.x); s0[1] += bf2f(g0.y); s0[2] += bf2f(g0.z); s0[3] += bf2f(g0.w);
    }
    float a0 = (s0[0] + s1[0]) + (s2[0] + s3[0]);
    float a1 = (s0[1] + s1[1]) + (s2[1] + s3[1]);
    float a2 = (s0[2] + s1[2]) + (s2[2] + s3[2]);
    float a3 = (s0[3] + s1[3]) + (s2[3] + s3[3]);

    float inv = 1.0f / fmaxf((float)d, 1.0f);
    ushort4 rh = ((const ushort4*)Hhi)[oidx];
    ushort4 rl = ((const ushort4*)Hlo)[oidx];
    float o0 = bf2f(rh.x) + bf2f(rl.x) + a0 * inv;
    float o1 = bf2f(rh.y) + bf2f(rl.y) + a1 * inv;
    float o2 = bf2f(rh.z) + bf2f(rl.z) + a2 * inv;
    float o3 = bf2f(rh.w) + bf2f(rl.w) + a3 * inv;

    ushort4 h4, l4;
    h4.x = f2bf(o0); l4.x = f2bf(o0 - bf2f(h4.x));
    h4.y = f2bf(o1); l4.y = f2bf(o1 - bf2f(h4.y));
    h4.z = f2bf(o2); l4.z = f2bf(o2 - bf2f(h4.z));
    h4.w = f2bf(o3); l4.w = f2bf(o3 - bf2f(h4.w));
    ((ushort4*)InHi)[oidx] = h4;
    ((ushort4*)InLo)[oidx] = l4;
}

extern "C" void kernel_launch(void* const* d_in, const int* in_sizes, int n_in,
                              void* d_out, int out_size, void* d_ws, size_t ws_size,
                              hipStream_t stream)
{
    const float* x  = (const float*)d_in[0];
    const int*   ei = (const int*)  d_in[1];
    const float* W0 = (const float*)d_in[2];
    const float* b0 = (const float*)d_in[3];
    const float* W1 = (const float*)d_in[4];
    const float* b1 = (const float*)d_in[5];
    const float* Wc = (const float*)d_in[6];
    const float* bc = (const float*)d_in[7];
    float* out = (float*)d_out;

    const int M    = in_sizes[0] / IN_DIM;   // 100000
    const int E    = in_sizes[1] / 2;        // 800000
    const int Mpad = (M + 63) & ~63;         // 100032
    const int NB   = (M + 255) / 256;        // 391

    // workspace layout
    ushort* Hhi  = (ushort*)d_ws;                        // Mpad*128
    ushort* Hlo  = Hhi  + (size_t)Mpad * 128;
    ushort* InHi = Hlo  + (size_t)Mpad * 128;
    ushort* InLo = InHi + (size_t)Mpad * 128;
    ushort* W0h  = InLo + (size_t)Mpad * 128;            // 16384 each
    ushort* W0l  = W0h + 16384;
    ushort* W1h  = W0l + 16384;
    ushort* W1l  = W1h + 16384;
    int* deg_i   = (int*)(W1l + 16384);                  // M
    int* off     = deg_i + M;                            // M
    int* pos     = off + M;                              // M
    int* bsum    = pos + M;                              // 512
    int* col_sorted = bsum + 512;                        // E

    const int* rows = ei;
    const int* cols = ei + E;

    hipMemsetAsync(deg_i, 0, (size_t)M * sizeof(int), stream);

    const int gridMM = Mpad / 64;            // 1563
    const int gridE  = (E + 255) / 256;
    const int gridN  = (M + 255) / 256;

    cast_w<<<128, 256, 0, stream>>>(W0, W1, W0h, W0l, W1h, W1l);
    gnn_lin0_mfma<<<gridMM, 256, 0, stream>>>(x, W0h, W0l, b0, Hhi, Hlo, M);

    count_deg<<<gridE, 256, 0, stream>>>(rows, deg_i, E);
    scan_blocks<<<gridN, 256, 0, stream>>>(deg_i, off, bsum, M);
    scan_bsum<<<1, 512, 0, stream>>>(bsum, NB);
    add_off<<<gridN, 256, 0, stream>>>(off, bsum, pos, M);
    fill_csr<<<gridE, 256, 0, stream>>>(rows, cols, pos, col_sorted, E);

    gnn_aggregate<<<(Mpad + 7) / 8, 256, 0, stream>>>(Hhi, Hlo, off, deg_i, col_sorted,
                                                      InHi, InLo, M, Mpad);
    gnn_lin1_mfma<<<gridMM, 256, 0, stream>>>(InHi, InLo, W1h, W1l, b1, Wc, bc, out, M);
}